// Round 3
// baseline (2570.086 us; speedup 1.0000x reference)
//
#include <hip/hip_runtime.h>
#include <hip/hip_bf16.h>

#define NN 16
#define CC 256
#define TT 64
#define VV 25
#define ICC 64
#define TV 1600      // TT*VV
#define CTV 409600   // CC*TV
#define ICTV 102400  // ICC*TV
#define NICTV 1638400

// ---------- prep: weight transpose: in [s][o][c][k] -> out [s][k][c][o]
__global__ void transpose_w_k(const float* __restrict__ in, float* __restrict__ out,
                              int O, int Cd, int K, int total){
  int i = blockIdx.x*256 + threadIdx.x;
  if (i >= total) return;
  int k = i % K; int r = i / K;
  int c = r % Cd; r /= Cd;
  int o = r % O;  int s = r / O;
  out[((s*K + k)*Cd + c)*O + o] = in[i];
}

// ---------- static graph transform: A_all[s] = ch3 + softmax_col(ch4) + PA
__global__ void a_all_k(const float* __restrict__ A, const float* __restrict__ PA,
                        float* __restrict__ Aall){
  int t = threadIdx.x;
  if (t >= 75) return;
  int s = t / 25, w = t % 25;
  float a[25], m[25];
  float mx = -3.4e38f;
  for (int v = 0; v < 25; ++v){
    float av = A[(s*25 + v)*25 + w];
    a[v] = av;
    float d = (v == w) ? 1.f : 0.f;
    float mm = (8.f*av*av*av*av - 4.f*av*av - 4.f*av + d) * 0.04f; // /25
    m[v] = mm;
    mx = fmaxf(mx, mm);
  }
  float sum = 0.f;
  for (int v = 0; v < 25; ++v){ float e = __expf(m[v]-mx); m[v] = e; sum += e; }
  float inv = 1.f/sum;
  for (int v = 0; v < 25; ++v){
    float av = a[v];
    float d = (v == w) ? 1.f : 0.f;
    Aall[(s*25+v)*25 + w] = m[v]*inv + 4.f*av*av - av - 2.f*d + PA[(s*25+v)*25+w];
  }
}

// ---------- init Ai3[br][n][v][w] = Aall[br][v][w]   (3*16*625 = 30000)
__global__ void init_ai3_k(float* __restrict__ Ai3, const float* __restrict__ Aall){
  int i = blockIdx.x*256 + threadIdx.x;
  if (i >= 30000) return;
  int br = i / 10000;
  int r  = i % 625;
  Ai3[i] = Aall[br*625 + r];
}

// ---------- conv1x1 pair: fbuf[which][n][o][t][v] = sum_c w[c][o]*x[n][c][t][v] + b[o]
// grid (5, 16, 16) block 320; weights f32 [c][o] (wave-uniform -> scalar loads)
__global__ __launch_bounds__(320) void conv1x1_pair_k(const float* __restrict__ x,
    const float* __restrict__ wA, const float* __restrict__ wB,
    const float* __restrict__ bA, const float* __restrict__ bB,
    float* __restrict__ fbuf){
  int p = blockIdx.x*320 + threadIdx.x;
  int which = blockIdx.y >> 3;
  int o0 = (blockIdx.y & 7) * 8;
  int n = blockIdx.z;
  const float* w    = which ? wB : wA;
  const float* bias = which ? bB : bA;
  const float* xp = x + n*CTV + p;
  float acc[8];
  #pragma unroll
  for (int j=0;j<8;++j) acc[j]=0.f;
  #pragma unroll 4
  for (int c=0;c<CC;++c){
    float xv = xp[c*TV];
    const float* wr = w + c*ICC + o0;
    #pragma unroll
    for (int j=0;j<8;++j) acc[j] = fmaf(xv, wr[j], acc[j]);
  }
  float* fo = fbuf + which*NICTV + n*ICTV + o0*TV + p;
  #pragma unroll
  for (int j=0;j<8;++j) fo[j*TV] = acc[j] + bias[o0+j];
}

// ---------- conv9 pair (temporal 9-tap, pad 4): weights f32 [k][c][o]
__global__ __launch_bounds__(320) void conv9_pair_k(const float* __restrict__ x,
    const float* __restrict__ wA, const float* __restrict__ wB,
    const float* __restrict__ bA, const float* __restrict__ bB,
    float* __restrict__ fbuf){
  int p = blockIdx.x*320 + threadIdx.x;
  int which = blockIdx.y >> 3;
  int o0 = (blockIdx.y & 7) * 8;
  int n = blockIdx.z;
  const float* w    = which ? wB : wA;
  const float* bias = which ? bB : bA;
  float acc[8];
  #pragma unroll
  for (int j=0;j<8;++j) acc[j]=0.f;
  for (int k=0;k<9;++k){
    int off = (k-4)*VV;
    bool valid = ((unsigned)(p+off) < (unsigned)TV);
    const float* xp = x + n*CTV + p + off;
    const float* wk = w + k*(CC*ICC) + o0;
    #pragma unroll 2
    for (int c=0;c<CC;++c){
      float xv = valid ? xp[c*TV] : 0.f;
      const float* wr = wk + c*ICC;
      #pragma unroll
      for (int j=0;j<8;++j) acc[j] = fmaf(xv, wr[j], acc[j]);
    }
  }
  float* fo = fbuf + which*NICTV + n*ICTV + o0*TV + p;
  #pragma unroll
  for (int j=0;j<8;++j) fo[j*TV] = acc[j] + bias[o0+j];
}

// ---------- attention scores for one pair, partial over q chunks (q = o*T+t, 4096 total)
// part[(n*16+chunk)*625 + v*25+w];  grid (16, 16), block 640
__global__ __launch_bounds__(640) void scores2_k(const float* __restrict__ fbuf,
                                                 float* __restrict__ part){
  __shared__ float s1[64*26];
  __shared__ float s2[64*26];
  int chunk = blockIdx.x, n = blockIdx.y;
  int tid = threadIdx.x;
  const float* f1 = fbuf + n*ICTV;
  const float* f2 = fbuf + NICTV + n*ICTV;
  int v = tid/25, w = tid%25;
  float acc = 0.f;
  for (int sub=0; sub<4; ++sub){
    int q0 = chunk*256 + sub*64;
    for (int l=tid; l<1600; l+=640){
      int qq = l/25, vv = l%25;
      s1[qq*26+vv] = f1[(q0+qq)*25+vv];
      s2[qq*26+vv] = f2[(q0+qq)*25+vv];
    }
    __syncthreads();
    if (tid < 625){
      #pragma unroll 8
      for (int q=0;q<64;++q) acc = fmaf(s1[q*26+v], s2[q*26+w], acc);
    }
    __syncthreads();
  }
  if (tid < 625) part[(n*16 + chunk)*625 + tid] = acc;
}

// ---------- reduce partials, column-softmax over v (axis -2), add into Ai slice
// grid (16, 25), block 64
__global__ __launch_bounds__(64) void reduce2_k(const float* __restrict__ part,
                                                float* __restrict__ Ai){
  int n = blockIdx.x, w = blockIdx.y;
  int lane = threadIdx.x;
  float s = 0.f;
  if (lane < 25){
    #pragma unroll
    for (int ch=0; ch<16; ++ch)
      s += part[(n*16 + ch)*625 + lane*25 + w];
  }
  s *= (1.f/4096.f);
  float mval = (lane<25) ? s : -3.4e38f;
  #pragma unroll
  for (int d=32; d>0; d>>=1) mval = fmaxf(mval, __shfl_xor(mval, d));
  float e = (lane<25) ? __expf(s - mval) : 0.f;
  float sum = e;
  #pragma unroll
  for (int d=32; d>0; d>>=1) sum += __shfl_xor(sum, d);
  if (lane < 25) Ai[n*625 + lane*25 + w] += e / sum;
}

// ---------- final fused: all 3 branches of (u = wd_i*x ; y += u*Ai_i + bd_i),
// then BN + residual + relu -> f32 out.  grid (T=64, N=16), block 128.
__global__ __launch_bounds__(128) void fused3_k(const float* __restrict__ x,
    const float* __restrict__ Ai3, const float* __restrict__ wdT,
    const float* __restrict__ bd, const float* __restrict__ gamma,
    const float* __restrict__ beta, const float* __restrict__ bnm,
    const float* __restrict__ bnv, float* __restrict__ out){
  __shared__ float xs[256*32];
  __shared__ float ais[3][25*28];
  int t = blockIdx.x, n = blockIdx.y, tid = threadIdx.x;
  for (int l=tid; l<1875; l+=128){
    int br = l/625, r = l%625;
    ais[br][(r/25)*28 + (r%25)] = Ai3[(br*NN + n)*625 + r];
  }
  for (int l=tid; l<6400; l+=128){
    int c = l/25, v = l%25;
    xs[c*32+v] = x[n*CTV + c*TV + t*VV + v];
  }
  __syncthreads();
  int o0 = tid*2, o1 = o0+1;
  float y0[25], y1[25];
  #pragma unroll
  for (int v=0;v<25;++v){ y0[v]=0.f; y1[v]=0.f; }
  for (int br=0; br<3; ++br){
    const float* wdb = wdT + br*65536;
    float u0[25], u1[25];
    #pragma unroll
    for (int v=0;v<25;++v){ u0[v]=0.f; u1[v]=0.f; }
    for (int c=0;c<CC;++c){
      float w0 = wdb[c*CC + o0];
      float w1 = wdb[c*CC + o1];
      const float* xr = xs + c*32;
      #pragma unroll
      for (int v=0;v<25;++v){ float xv = xr[v]; u0[v]=fmaf(w0,xv,u0[v]); u1[v]=fmaf(w1,xv,u1[v]); }
    }
    float b0v = bd[br*256 + o0];
    float b1v = bd[br*256 + o1];
    const float* ab = ais[br];
    for (int w=0; w<25; ++w){
      float a0=b0v, a1=b1v;
      #pragma unroll
      for (int v=0;v<25;++v){ float av = ab[v*28+w]; a0=fmaf(u0[v],av,a0); a1=fmaf(u1[v],av,a1); }
      y0[w] += a0; y1[w] += a1;
    }
  }
  float sc0 = gamma[o0] * rsqrtf(bnv[o0] + 1e-5f);
  float sc1 = gamma[o1] * rsqrtf(bnv[o1] + 1e-5f);
  float m0 = bnm[o0], m1 = bnm[o1];
  float be0 = beta[o0], be1 = beta[o1];
  float* out0 = out + n*CTV + o0*TV + t*VV;
  float* out1 = out0 + TV;
  for (int w=0; w<25; ++w){
    float v0 = (y0[w] - m0)*sc0 + be0 + xs[o0*32 + w];
    float v1 = (y1[w] - m1)*sc1 + be1 + xs[o1*32 + w];
    out0[w] = fmaxf(v0, 0.f);
    out1[w] = fmaxf(v1, 0.f);
  }
}

extern "C" void kernel_launch(void* const* d_in, const int* in_sizes, int n_in,
                              void* d_out, int out_size, void* d_ws, size_t ws_size,
                              hipStream_t stream) {
  const float* x     = (const float*)d_in[0];
  const float* A     = (const float*)d_in[1];
  const float* PA    = (const float*)d_in[2];
  const float* wa    = (const float*)d_in[3];
  const float* ba    = (const float*)d_in[4];
  const float* wb    = (const float*)d_in[5];
  const float* bb    = (const float*)d_in[6];
  const float* wT1   = (const float*)d_in[7];
  const float* bT1   = (const float*)d_in[8];
  const float* wT2   = (const float*)d_in[9];
  const float* bT2   = (const float*)d_in[10];
  const float* wST11 = (const float*)d_in[11];
  const float* bST11 = (const float*)d_in[12];
  const float* wST12 = (const float*)d_in[13];
  const float* bST12 = (const float*)d_in[14];
  const float* wd    = (const float*)d_in[15];
  const float* bd    = (const float*)d_in[16];
  const float* gamma = (const float*)d_in[17];
  const float* beta  = (const float*)d_in[18];
  const float* bnm   = (const float*)d_in[19];
  const float* bnv   = (const float*)d_in[20];

  float* ws   = (float*)d_ws;
  float* waT  = ws;                    // 3*256*64   = 49152
  float* wbT  = waT  + 49152;
  float* wT1T = wbT  + 49152;          // 3*9*256*64 = 442368
  float* wT2T = wT1T + 442368;
  float* wS1T = wT2T + 442368;
  float* wS2T = wS1T + 442368;
  float* wdT  = wS2T + 442368;         // 3*256*256  = 196608
  float* Aall = wdT  + 196608;         // 1875 (pad 2048)
  float* Ai3  = Aall + 2048;           // 30000 (pad 30720)
  float* part = Ai3  + 30720;          // 16*16*625 = 160000 (pad 163840)
  float* fbuf = part + 163840;         // 2*16*102400 = 3276800
  // total ~5.54M floats ~22.2 MB

  transpose_w_k<<<(49152+255)/256, 256, 0, stream>>>(wa, waT, 64, 256, 1, 49152);
  transpose_w_k<<<(49152+255)/256, 256, 0, stream>>>(wb, wbT, 64, 256, 1, 49152);
  transpose_w_k<<<(442368+255)/256, 256, 0, stream>>>(wT1, wT1T, 64, 256, 9, 442368);
  transpose_w_k<<<(442368+255)/256, 256, 0, stream>>>(wT2, wT2T, 64, 256, 9, 442368);
  transpose_w_k<<<(442368+255)/256, 256, 0, stream>>>(wST11, wS1T, 64, 256, 9, 442368);
  transpose_w_k<<<(442368+255)/256, 256, 0, stream>>>(wST12, wS2T, 64, 256, 9, 442368);
  transpose_w_k<<<(196608+255)/256, 256, 0, stream>>>(wd, wdT, 256, 256, 1, 196608);
  a_all_k<<<1, 128, 0, stream>>>(A, PA, Aall);
  init_ai3_k<<<118, 256, 0, stream>>>(Ai3, Aall);

  for (int i = 0; i < 3; ++i){
    bool even = (i % 2 == 0);
    float* Ai = Ai3 + i*(NN*625);
    // pair A: 1x1 convs
    conv1x1_pair_k<<<dim3(5,16,16), 320, 0, stream>>>(x,
        waT + i*16384, wbT + i*16384, ba + i*64, bb + i*64, fbuf);
    scores2_k<<<dim3(16,16), 640, 0, stream>>>(fbuf, part);
    reduce2_k<<<dim3(16,25), 64, 0, stream>>>(part, Ai);
    // pair T: 9-tap convs
    conv9_pair_k<<<dim3(5,16,16), 320, 0, stream>>>(x,
        wT1T + i*147456, wT2T + i*147456, bT1 + i*64, bT2 + i*64, fbuf);
    scores2_k<<<dim3(16,16), 640, 0, stream>>>(fbuf, part);
    reduce2_k<<<dim3(16,25), 64, 0, stream>>>(part, Ai);
    // pair ST: even -> center-tap 1x1 (k=4), odd -> 9-tap
    if (even){
      conv1x1_pair_k<<<dim3(5,16,16), 320, 0, stream>>>(x,
          wS1T + i*147456 + 4*16384, wS2T + i*147456 + 4*16384,
          bST11 + i*64, bST12 + i*64, fbuf);
    } else {
      conv9_pair_k<<<dim3(5,16,16), 320, 0, stream>>>(x,
          wS1T + i*147456, wS2T + i*147456, bST11 + i*64, bST12 + i*64, fbuf);
    }
    scores2_k<<<dim3(16,16), 640, 0, stream>>>(fbuf, part);
    reduce2_k<<<dim3(16,25), 64, 0, stream>>>(part, Ai);
  }
  fused3_k<<<dim3(64,16), 128, 0, stream>>>(x, Ai3, wdT, bd, gamma, beta, bnm, bnv,
                                            (float*)d_out);
}

// Round 4
// 975.212 us; speedup vs baseline: 2.6354x; 2.6354x over previous
//
#include <hip/hip_runtime.h>
#include <hip/hip_bf16.h>

#define NN 16
#define CC 256
#define TT 64
#define VV 25
#define ICC 64
#define TV 1600      // TT*VV
#define CTV 409600   // CC*TV
#define ICTV 102400  // ICC*TV
#define NICTV 1638400

typedef __bf16 v8bf __attribute__((ext_vector_type(8)));
typedef float f32x16 __attribute__((ext_vector_type(16)));

// ---------- x transpose to channels-last bf16: xt[n][p][c] = x[n][c][p]
__global__ __launch_bounds__(256) void xt_k(const float* __restrict__ x,
                                            __bf16* __restrict__ xt){
  __shared__ float tile[64][65];
  int p0 = blockIdx.x*64, c0 = blockIdx.y*64, n = blockIdx.z;
  int tid = threadIdx.x;
  for (int i = tid; i < 4096; i += 256){
    int cc = i >> 6, pp = i & 63;
    tile[cc][pp] = x[(size_t)n*CTV + (size_t)(c0+cc)*TV + p0 + pp];
  }
  __syncthreads();
  for (int i = tid; i < 4096; i += 256){
    int pp = i >> 6, cc = i & 63;
    xt[((size_t)n*TV + p0+pp)*256 + c0+cc] = (__bf16)tile[cc][pp];
  }
}

// ---------- conv weights [3][64][256][9] f32 -> [3][64][9][256] bf16
__global__ void wcvt9_k(const float* __restrict__ in, __bf16* __restrict__ out){
  int i = blockIdx.x*256 + threadIdx.x;
  if (i >= 442368) return;
  int c = i & 255;
  int k = (i >> 8) % 9;
  int r = i / 2304;            // s*64+o
  out[i] = (__bf16)in[(r*256 + c)*9 + k];
}

// ---------- conv weights [3][64][256] f32 -> bf16 (same layout)
__global__ void wcvt1_k(const float* __restrict__ in, __bf16* __restrict__ out){
  int i = blockIdx.x*256 + threadIdx.x;
  if (i < 49152) out[i] = (__bf16)in[i];
}

// ---------- wd transpose (f32): in [s][o][c] -> out [s][c][o]
__global__ void transpose_w_k(const float* __restrict__ in, float* __restrict__ out,
                              int O, int Cd, int K, int total){
  int i = blockIdx.x*256 + threadIdx.x;
  if (i >= total) return;
  int k = i % K; int r = i / K;
  int c = r % Cd; r /= Cd;
  int o = r % O;  int s = r / O;
  out[((s*K + k)*Cd + c)*O + o] = in[i];
}

// ---------- static graph transform: A_all[s] = ch3 + softmax_col(ch4) + PA
__global__ void a_all_k(const float* __restrict__ A, const float* __restrict__ PA,
                        float* __restrict__ Aall){
  int t = threadIdx.x;
  if (t >= 75) return;
  int s = t / 25, w = t % 25;
  float a[25], m[25];
  float mx = -3.4e38f;
  for (int v = 0; v < 25; ++v){
    float av = A[(s*25 + v)*25 + w];
    a[v] = av;
    float d = (v == w) ? 1.f : 0.f;
    float mm = (8.f*av*av*av*av - 4.f*av*av - 4.f*av + d) * 0.04f;
    m[v] = mm;
    mx = fmaxf(mx, mm);
  }
  float sum = 0.f;
  for (int v = 0; v < 25; ++v){ float e = __expf(m[v]-mx); m[v] = e; sum += e; }
  float inv = 1.f/sum;
  for (int v = 0; v < 25; ++v){
    float av = a[v];
    float d = (v == w) ? 1.f : 0.f;
    Aall[(s*25+v)*25 + w] = m[v]*inv + 4.f*av*av - av - 2.f*d + PA[(s*25+v)*25+w];
  }
}

__global__ void init_ai3_k(float* __restrict__ Ai3, const float* __restrict__ Aall){
  int i = blockIdx.x*256 + threadIdx.x;
  if (i >= 30000) return;
  int br = i / 10000;
  int r  = i % 625;
  Ai3[i] = Aall[br*625 + r];
}

// ---------- MFMA conv pair: fbuf[which][n][o][p] = sum_K w[o][K] * xt[n][p+off][c] + b
// Output tile per WG: 128 rows (2 which x 64 o) x 64 p, one n. 8 waves of 32x32 quadrants.
// A = W (m=o, K-runs contiguous c), B = X from LDS slab (col=p), D cols = p (coalesced).
template<int NTAPS, int CW>
__global__ __launch_bounds__(512) void conv_mfma_k(const __bf16* __restrict__ xt,
    const __bf16* __restrict__ wA, const __bf16* __restrict__ wB,
    const float* __restrict__ bA, const float* __restrict__ bB,
    __bf16* __restrict__ fbuf, int wstride, int tapbase){
  extern __shared__ __bf16 sm[];
  constexpr int NROWS = (NTAPS==9) ? 264 : 64;
  constexpr int HALO  = (NTAPS==9) ? 100 : 0;
  constexpr int GPR   = CW/8;            // 16B groups per LDS row
  constexpr int NCH   = 256/CW;          // c chunks
  int p0 = blockIdx.x*64;
  int n  = blockIdx.y;
  int tid = threadIdx.x;
  int lane = tid & 63;
  int wave = tid >> 6;
  int pq = wave & 1, oq = wave >> 1;
  int which = oq >> 1;
  int h = lane >> 5, l31 = lane & 31;
  const __bf16* wgt = which ? wB : wA;
  const float* bias = which ? bB : bA;
  int orow = (oq & 1)*32 + l31;
  const __bf16* xtn = xt + (size_t)n*CTV;

  f32x16 acc;
  #pragma unroll
  for (int r=0;r<16;++r) acc[r] = 0.f;

  for (int ch=0; ch<NCH; ++ch){
    // stage slab chunk: NROWS x CW bf16, group-swizzled (g' = (g+row)&(GPR-1))
    for (int s2 = tid; s2 < NROWS*GPR; s2 += 512){
      int row = s2 / GPR, g = s2 % GPR;
      int pg = p0 - HALO + row;
      uint4 val = make_uint4(0u,0u,0u,0u);
      if ((unsigned)pg < 1600u)
        val = *(const uint4*)(xtn + (size_t)pg*256 + ch*CW + g*8);
      int gs = (g + row) & (GPR-1);
      *(uint4*)(sm + row*CW + gs*8) = val;
    }
    __syncthreads();
    const __bf16* wch = wgt + (size_t)orow*wstride + ch*CW;
    for (int tap=0; tap<NTAPS; ++tap){
      int rowbase = (NTAPS==9 ? tap*25 : 0) + pq*32;
      const __bf16* wr = wch + (size_t)(tapbase+tap)*256;
      #pragma unroll 4
      for (int ks=0; ks<CW/16; ++ks){
        v8bf a = *(const v8bf*)(wr + ks*16 + h*8);
        int row = rowbase + l31;
        int gs = ((ks*2 + h) + row) & (GPR-1);
        v8bf b = *(const v8bf*)(sm + row*CW + gs*8);
        acc = __builtin_amdgcn_mfma_f32_32x32x16_bf16(a, b, acc, 0, 0, 0);
      }
    }
    __syncthreads();
  }

  // epilogue: D col = lane&31 -> p (coalesced), row = (r&3)+8*(r>>2)+4*h -> o
  int p = p0 + pq*32 + l31;
  __bf16* out = fbuf + (size_t)which*NICTV + (size_t)n*ICTV + p;
  #pragma unroll
  for (int r=0; r<16; ++r){
    int ol = (r&3) + 8*(r>>2) + 4*h;
    int og = (oq&1)*32 + ol;
    out[(size_t)og*TV] = (__bf16)(acc[r] + bias[og]);
  }
}

// ---------- attention scores (bf16 f-tensors), partial over q chunks
// part[(n*16+chunk)*625 + v*25+w];  grid (16, 16), block 640
__global__ __launch_bounds__(640) void scores2_k(const __bf16* __restrict__ fbuf,
                                                 float* __restrict__ part){
  __shared__ float s1[64*26];
  __shared__ float s2[64*26];
  int chunk = blockIdx.x, n = blockIdx.y;
  int tid = threadIdx.x;
  const __bf16* f1 = fbuf + (size_t)n*ICTV;
  const __bf16* f2 = fbuf + NICTV + (size_t)n*ICTV;
  int v = tid/25, w = tid%25;
  float acc = 0.f;
  for (int sub=0; sub<4; ++sub){
    int q0 = chunk*256 + sub*64;
    for (int l=tid; l<1600; l+=640){
      int qq = l/25, vv = l%25;
      s1[qq*26+vv] = (float)f1[(q0+qq)*25+vv];
      s2[qq*26+vv] = (float)f2[(q0+qq)*25+vv];
    }
    __syncthreads();
    if (tid < 625){
      #pragma unroll 8
      for (int q=0;q<64;++q) acc = fmaf(s1[q*26+v], s2[q*26+w], acc);
    }
    __syncthreads();
  }
  if (tid < 625) part[(n*16 + chunk)*625 + tid] = acc;
}

// ---------- reduce partials, column-softmax over v (axis -2), add into Ai slice
__global__ __launch_bounds__(64) void reduce2_k(const float* __restrict__ part,
                                                float* __restrict__ Ai){
  int n = blockIdx.x, w = blockIdx.y;
  int lane = threadIdx.x;
  float s = 0.f;
  if (lane < 25){
    #pragma unroll
    for (int ch=0; ch<16; ++ch)
      s += part[(n*16 + ch)*625 + lane*25 + w];
  }
  s *= (1.f/4096.f);
  float mval = (lane<25) ? s : -3.4e38f;
  #pragma unroll
  for (int d=32; d>0; d>>=1) mval = fmaxf(mval, __shfl_xor(mval, d));
  float e = (lane<25) ? __expf(s - mval) : 0.f;
  float sum = e;
  #pragma unroll
  for (int d=32; d>0; d>>=1) sum += __shfl_xor(sum, d);
  if (lane < 25) Ai[n*625 + lane*25 + w] += e / sum;
}

// ---------- final fused: 3 branches of (u = wd_i*x ; y += u*Ai_i + bd_i),
// then BN + residual + relu -> f32 out.  grid (T=64, N=16), block 128.
__global__ __launch_bounds__(128) void fused3_k(const float* __restrict__ x,
    const float* __restrict__ Ai3, const float* __restrict__ wdT,
    const float* __restrict__ bd, const float* __restrict__ gamma,
    const float* __restrict__ beta, const float* __restrict__ bnm,
    const float* __restrict__ bnv, float* __restrict__ out){
  __shared__ float xs[256*32];
  __shared__ float ais[3][25*28];
  int t = blockIdx.x, n = blockIdx.y, tid = threadIdx.x;
  for (int l=tid; l<1875; l+=128){
    int br = l/625, r = l%625;
    ais[br][(r/25)*28 + (r%25)] = Ai3[(br*NN + n)*625 + r];
  }
  for (int l=tid; l<6400; l+=128){
    int c = l/25, v = l%25;
    xs[c*32+v] = x[(size_t)n*CTV + (size_t)c*TV + t*VV + v];
  }
  __syncthreads();
  int o0 = tid*2, o1 = o0+1;
  float y0[25], y1[25];
  #pragma unroll
  for (int v=0;v<25;++v){ y0[v]=0.f; y1[v]=0.f; }
  for (int br=0; br<3; ++br){
    const float* wdb = wdT + br*65536;
    float u0[25], u1[25];
    #pragma unroll
    for (int v=0;v<25;++v){ u0[v]=0.f; u1[v]=0.f; }
    for (int c=0;c<CC;++c){
      float w0 = wdb[c*CC + o0];
      float w1 = wdb[c*CC + o1];
      const float* xr = xs + c*32;
      #pragma unroll
      for (int v=0;v<25;++v){ float xv = xr[v]; u0[v]=fmaf(w0,xv,u0[v]); u1[v]=fmaf(w1,xv,u1[v]); }
    }
    float b0v = bd[br*256 + o0];
    float b1v = bd[br*256 + o1];
    const float* ab = ais[br];
    for (int w=0; w<25; ++w){
      float a0=b0v, a1=b1v;
      #pragma unroll
      for (int v=0;v<25;++v){ float av = ab[v*28+w]; a0=fmaf(u0[v],av,a0); a1=fmaf(u1[v],av,a1); }
      y0[w] += a0; y1[w] += a1;
    }
  }
  float sc0 = gamma[o0] * rsqrtf(bnv[o0] + 1e-5f);
  float sc1 = gamma[o1] * rsqrtf(bnv[o1] + 1e-5f);
  float m0 = bnm[o0], m1 = bnm[o1];
  float be0 = beta[o0], be1 = beta[o1];
  float* out0 = out + (size_t)n*CTV + (size_t)o0*TV + t*VV;
  float* out1 = out0 + TV;
  for (int w=0; w<25; ++w){
    float v0 = (y0[w] - m0)*sc0 + be0 + xs[o0*32 + w];
    float v1 = (y1[w] - m1)*sc1 + be1 + xs[o1*32 + w];
    out0[w] = fmaxf(v0, 0.f);
    out1[w] = fmaxf(v1, 0.f);
  }
}

extern "C" void kernel_launch(void* const* d_in, const int* in_sizes, int n_in,
                              void* d_out, int out_size, void* d_ws, size_t ws_size,
                              hipStream_t stream) {
  const float* x     = (const float*)d_in[0];
  const float* A     = (const float*)d_in[1];
  const float* PA    = (const float*)d_in[2];
  const float* wa    = (const float*)d_in[3];
  const float* ba    = (const float*)d_in[4];
  const float* wb    = (const float*)d_in[5];
  const float* bb    = (const float*)d_in[6];
  const float* wT1   = (const float*)d_in[7];
  const float* bT1   = (const float*)d_in[8];
  const float* wT2   = (const float*)d_in[9];
  const float* bT2   = (const float*)d_in[10];
  const float* wST11 = (const float*)d_in[11];
  const float* bST11 = (const float*)d_in[12];
  const float* wST12 = (const float*)d_in[13];
  const float* bST12 = (const float*)d_in[14];
  const float* wd    = (const float*)d_in[15];
  const float* bd    = (const float*)d_in[16];
  const float* gamma = (const float*)d_in[17];
  const float* beta  = (const float*)d_in[18];
  const float* bnm   = (const float*)d_in[19];
  const float* bnv   = (const float*)d_in[20];

  char* W = (char*)d_ws;
  float*  wdT  = (float*)W;  W += 786432;    // 3*256*256 f32
  float*  Aall = (float*)W;  W += 8192;
  float*  Ai3  = (float*)W;  W += 122880;    // 3*16*625 f32 (padded)
  float*  part = (float*)W;  W += 655360;    // 16*16*625 f32 (padded)
  __bf16* fbuf = (__bf16*)W; W += 6553600;   // 2*16*64*1600 bf16
  __bf16* xt   = (__bf16*)W; W += 13107200;  // 16*1600*256 bf16
  __bf16* wab  = (__bf16*)W; W += 98304;     // 3*64*256 bf16
  __bf16* wbb  = (__bf16*)W; W += 98304;
  __bf16* wT1b = (__bf16*)W; W += 884736;    // 3*64*9*256 bf16
  __bf16* wT2b = (__bf16*)W; W += 884736;
  __bf16* wS1b = (__bf16*)W; W += 884736;
  __bf16* wS2b = (__bf16*)W; W += 884736;
  // total ~25.0 MB

  // prep
  xt_k<<<dim3(25,4,16), 256, 0, stream>>>(x, xt);
  wcvt1_k<<<192, 256, 0, stream>>>(wa, wab);
  wcvt1_k<<<192, 256, 0, stream>>>(wb, wbb);
  wcvt9_k<<<1728, 256, 0, stream>>>(wT1, wT1b);
  wcvt9_k<<<1728, 256, 0, stream>>>(wT2, wT2b);
  wcvt9_k<<<1728, 256, 0, stream>>>(wST11, wS1b);
  wcvt9_k<<<1728, 256, 0, stream>>>(wST12, wS2b);
  transpose_w_k<<<768, 256, 0, stream>>>(wd, wdT, 256, 256, 1, 196608);
  a_all_k<<<1, 128, 0, stream>>>(A, PA, Aall);
  init_ai3_k<<<118, 256, 0, stream>>>(Ai3, Aall);

  for (int i = 0; i < 3; ++i){
    bool even = (i % 2 == 0);
    float* Ai = Ai3 + i*(NN*625);
    // pair A: 1x1 convs (weights [s][o][256], row stride 256)
    conv_mfma_k<1,256><<<dim3(25,16), 512, 64*256*2, stream>>>(xt,
        wab + i*16384, wbb + i*16384, ba + i*64, bb + i*64, fbuf, 256, 0);
    scores2_k<<<dim3(16,16), 640, 0, stream>>>(fbuf, part);
    reduce2_k<<<dim3(16,25), 64, 0, stream>>>(part, Ai);
    // pair T: 9-tap convs (weights [s][o][9][256], row stride 2304)
    conv_mfma_k<9,64><<<dim3(25,16), 512, 264*64*2, stream>>>(xt,
        wT1b + i*147456, wT2b + i*147456, bT1 + i*64, bT2 + i*64, fbuf, 2304, 0);
    scores2_k<<<dim3(16,16), 640, 0, stream>>>(fbuf, part);
    reduce2_k<<<dim3(16,25), 64, 0, stream>>>(part, Ai);
    // pair ST: even -> center tap (tapbase=4) of 9-tap weights; odd -> full 9-tap
    if (even){
      conv_mfma_k<1,256><<<dim3(25,16), 512, 64*256*2, stream>>>(xt,
          wS1b + i*147456, wS2b + i*147456, bST11 + i*64, bST12 + i*64, fbuf, 2304, 4);
    } else {
      conv_mfma_k<9,64><<<dim3(25,16), 512, 264*64*2, stream>>>(xt,
          wS1b + i*147456, wS2b + i*147456, bST11 + i*64, bST12 + i*64, fbuf, 2304, 0);
    }
    scores2_k<<<dim3(16,16), 640, 0, stream>>>(fbuf, part);
    reduce2_k<<<dim3(16,25), 64, 0, stream>>>(part, Ai);
  }
  fused3_k<<<dim3(64,16), 128, 0, stream>>>(x, Ai3, wdT, bd, gamma, beta, bnm, bnv,
                                            (float*)d_out);
}

// Round 5
// 715.732 us; speedup vs baseline: 3.5909x; 1.3625x over previous
//
#include <hip/hip_runtime.h>
#include <hip/hip_bf16.h>

#define NN 16
#define CC 256
#define TT 64
#define VV 25
#define ICC 64
#define TV 1600      // TT*VV
#define CTV 409600   // CC*TV
#define ICTV 102400  // ICC*TV
#define NICTV 1638400

typedef __bf16 v8bf __attribute__((ext_vector_type(8)));
typedef __bf16 v4bf __attribute__((ext_vector_type(4)));
typedef float f32x16 __attribute__((ext_vector_type(16)));

// ---------- x transpose to channels-last bf16: xt[n][p][c] = x[n][c][p]
__global__ __launch_bounds__(256) void xt_k(const float* __restrict__ x,
                                            __bf16* __restrict__ xt){
  __shared__ float tile[64][65];
  int p0 = blockIdx.x*64, c0 = blockIdx.y*64, n = blockIdx.z;
  int tid = threadIdx.x;
  for (int i = tid; i < 4096; i += 256){
    int cc = i >> 6, pp = i & 63;
    tile[cc][pp] = x[(size_t)n*CTV + (size_t)(c0+cc)*TV + p0 + pp];
  }
  __syncthreads();
  for (int i = tid; i < 4096; i += 256){
    int pp = i >> 6, cc = i & 63;
    xt[((size_t)n*TV + p0+pp)*256 + c0+cc] = (__bf16)tile[cc][pp];
  }
}

// ---------- conv weights [3][64][256][9] f32 -> [3][64][9][256] bf16
__global__ void wcvt9_k(const float* __restrict__ in, __bf16* __restrict__ out){
  int i = blockIdx.x*256 + threadIdx.x;
  if (i >= 442368) return;
  int c = i & 255;
  int k = (i >> 8) % 9;
  int r = i / 2304;            // s*64+o
  out[i] = (__bf16)in[(r*256 + c)*9 + k];
}

// ---------- f32 -> bf16 straight convert
__global__ void wcvt_k(const float* __restrict__ in, __bf16* __restrict__ out, int total){
  int i = blockIdx.x*256 + threadIdx.x;
  if (i < total) out[i] = (__bf16)in[i];
}

// ---------- static graph transform: A_all[s] = ch3 + softmax_col(ch4) + PA
__global__ void a_all_k(const float* __restrict__ A, const float* __restrict__ PA,
                        float* __restrict__ Aall){
  int t = threadIdx.x;
  if (t >= 75) return;
  int s = t / 25, w = t % 25;
  float a[25], m[25];
  float mx = -3.4e38f;
  for (int v = 0; v < 25; ++v){
    float av = A[(s*25 + v)*25 + w];
    a[v] = av;
    float d = (v == w) ? 1.f : 0.f;
    float mm = (8.f*av*av*av*av - 4.f*av*av - 4.f*av + d) * 0.04f;
    m[v] = mm;
    mx = fmaxf(mx, mm);
  }
  float sum = 0.f;
  for (int v = 0; v < 25; ++v){ float e = __expf(m[v]-mx); m[v] = e; sum += e; }
  float inv = 1.f/sum;
  for (int v = 0; v < 25; ++v){
    float av = a[v];
    float d = (v == w) ? 1.f : 0.f;
    Aall[(s*25+v)*25 + w] = m[v]*inv + 4.f*av*av - av - 2.f*d + PA[(s*25+v)*25+w];
  }
}

__global__ void init_ai3_k(float* __restrict__ Ai3, const float* __restrict__ Aall){
  int i = blockIdx.x*256 + threadIdx.x;
  if (i >= 30000) return;
  int br = i / 10000;
  int r  = i % 625;
  Ai3[i] = Aall[br*625 + r];
}

// ---------- MFMA conv pair: fbuf[which][n][o][p] = sum_K w[o][K] * xt[n][p+off][c] + b
template<int NTAPS, int CW>
__global__ __launch_bounds__(512) void conv_mfma_k(const __bf16* __restrict__ xt,
    const __bf16* __restrict__ wA, const __bf16* __restrict__ wB,
    const float* __restrict__ bA, const float* __restrict__ bB,
    __bf16* __restrict__ fbuf, int wstride, int tapbase){
  extern __shared__ __bf16 sm[];
  constexpr int NROWS = (NTAPS==9) ? 264 : 64;
  constexpr int HALO  = (NTAPS==9) ? 100 : 0;
  constexpr int GPR   = CW/8;
  constexpr int NCH   = 256/CW;
  int p0 = blockIdx.x*64;
  int n  = blockIdx.y;
  int tid = threadIdx.x;
  int lane = tid & 63;
  int wave = tid >> 6;
  int pq = wave & 1, oq = wave >> 1;
  int which = oq >> 1;
  int h = lane >> 5, l31 = lane & 31;
  const __bf16* wgt = which ? wB : wA;
  const float* bias = which ? bB : bA;
  int orow = (oq & 1)*32 + l31;
  const __bf16* xtn = xt + (size_t)n*CTV;

  f32x16 acc;
  #pragma unroll
  for (int r=0;r<16;++r) acc[r] = 0.f;

  for (int ch=0; ch<NCH; ++ch){
    for (int s2 = tid; s2 < NROWS*GPR; s2 += 512){
      int row = s2 / GPR, g = s2 % GPR;
      int pg = p0 - HALO + row;
      uint4 val = make_uint4(0u,0u,0u,0u);
      if ((unsigned)pg < 1600u)
        val = *(const uint4*)(xtn + (size_t)pg*256 + ch*CW + g*8);
      int gs = (g + row) & (GPR-1);
      *(uint4*)(sm + row*CW + gs*8) = val;
    }
    __syncthreads();
    const __bf16* wch = wgt + (size_t)orow*wstride + ch*CW;
    for (int tap=0; tap<NTAPS; ++tap){
      int rowbase = (NTAPS==9 ? tap*25 : 0) + pq*32;
      const __bf16* wr = wch + (size_t)(tapbase+tap)*256;
      #pragma unroll 4
      for (int ks=0; ks<CW/16; ++ks){
        v8bf a = *(const v8bf*)(wr + ks*16 + h*8);
        int row = rowbase + l31;
        int gs = ((ks*2 + h) + row) & (GPR-1);
        v8bf b = *(const v8bf*)(sm + row*CW + gs*8);
        acc = __builtin_amdgcn_mfma_f32_32x32x16_bf16(a, b, acc, 0, 0, 0);
      }
    }
    __syncthreads();
  }

  int p = p0 + pq*32 + l31;
  __bf16* out = fbuf + (size_t)which*NICTV + (size_t)n*ICTV + p;
  #pragma unroll
  for (int r=0; r<16; ++r){
    int ol = (r&3) + 8*(r>>2) + 4*h;
    int og = (oq&1)*32 + ol;
    out[(size_t)og*TV] = (__bf16)(acc[r] + bias[og]);
  }
}

// ---------- u GEMM: ubuf[br][n][p][o] = sum_c wd[br][o][c] * xt[n][p][c]  (no bias)
// grid (25, 16, 6): z = br*2 + half(o 0..127 / 128..255). 8 waves: 2 p-halves x 4 o-quads.
__global__ __launch_bounds__(512) void ugemm_k(const __bf16* __restrict__ xt,
    const __bf16* __restrict__ wdb, __bf16* __restrict__ ubuf){
  __shared__ __bf16 sm[64*256];
  int p0 = blockIdx.x*64;
  int n  = blockIdx.y;
  int br = blockIdx.z >> 1, half = blockIdx.z & 1;
  int tid = threadIdx.x;
  int lane = tid & 63;
  int wave = tid >> 6;
  int pq = wave & 1, oq = wave >> 1;
  int h = lane >> 5, l31 = lane & 31;
  const __bf16* xtn = xt + (size_t)n*CTV;

  f32x16 acc;
  #pragma unroll
  for (int r=0;r<16;++r) acc[r] = 0.f;

  // stage 64 x 256 slab, group-swizzled
  for (int s2 = tid; s2 < 64*32; s2 += 512){
    int row = s2 >> 5, g = s2 & 31;
    uint4 val = *(const uint4*)(xtn + (size_t)(p0+row)*256 + g*8);
    int gs = (g + row) & 31;
    *(uint4*)(sm + row*256 + gs*8) = val;
  }
  __syncthreads();

  const __bf16* wr = wdb + ((size_t)br*256 + half*128 + oq*32 + l31)*256;
  #pragma unroll 4
  for (int ks=0; ks<16; ++ks){
    v8bf a = *(const v8bf*)(wr + ks*16 + h*8);
    int row = pq*32 + l31;
    int gs = ((ks*2 + h) + row) & 31;
    v8bf b = *(const v8bf*)(sm + row*256 + gs*8);
    acc = __builtin_amdgcn_mfma_f32_32x32x16_bf16(a, b, acc, 0, 0, 0);
  }

  // store o-contiguous: ubuf[((br*16+n)*1600 + p)*256 + og], packed 4-wide
  int p = p0 + pq*32 + l31;
  __bf16* out = ubuf + ((size_t)(br*NN + n)*TV + p)*256;
  #pragma unroll
  for (int g=0; g<4; ++g){
    int og0 = half*128 + oq*32 + 8*g + 4*h;
    v4bf pk;
    pk[0] = (__bf16)acc[4*g+0];
    pk[1] = (__bf16)acc[4*g+1];
    pk[2] = (__bf16)acc[4*g+2];
    pk[3] = (__bf16)acc[4*g+3];
    *(v4bf*)(out + og0) = pk;
  }
}

// ---------- attention scores (bf16 f-tensors), partial over q chunks
__global__ __launch_bounds__(640) void scores2_k(const __bf16* __restrict__ fbuf,
                                                 float* __restrict__ part){
  __shared__ float s1[64*26];
  __shared__ float s2[64*26];
  int chunk = blockIdx.x, n = blockIdx.y;
  int tid = threadIdx.x;
  const __bf16* f1 = fbuf + (size_t)n*ICTV;
  const __bf16* f2 = fbuf + NICTV + (size_t)n*ICTV;
  int v = tid/25, w = tid%25;
  float acc = 0.f;
  for (int sub=0; sub<4; ++sub){
    int q0 = chunk*256 + sub*64;
    for (int l=tid; l<1600; l+=640){
      int qq = l/25, vv = l%25;
      s1[qq*26+vv] = (float)f1[(q0+qq)*25+vv];
      s2[qq*26+vv] = (float)f2[(q0+qq)*25+vv];
    }
    __syncthreads();
    if (tid < 625){
      #pragma unroll 8
      for (int q=0;q<64;++q) acc = fmaf(s1[q*26+v], s2[q*26+w], acc);
    }
    __syncthreads();
  }
  if (tid < 625) part[(n*16 + chunk)*625 + tid] = acc;
}

// ---------- reduce partials, column-softmax over v (axis -2), add into Ai slice
__global__ __launch_bounds__(64) void reduce2_k(const float* __restrict__ part,
                                                float* __restrict__ Ai){
  int n = blockIdx.x, w = blockIdx.y;
  int lane = threadIdx.x;
  float s = 0.f;
  if (lane < 25){
    #pragma unroll
    for (int ch=0; ch<16; ++ch)
      s += part[(n*16 + ch)*625 + lane*25 + w];
  }
  s *= (1.f/4096.f);
  float mval = (lane<25) ? s : -3.4e38f;
  #pragma unroll
  for (int d=32; d>0; d>>=1) mval = fmaxf(mval, __shfl_xor(mval, d));
  float e = (lane<25) ? __expf(s - mval) : 0.f;
  float sum = e;
  #pragma unroll
  for (int d=32; d>0; d>>=1) sum += __shfl_xor(sum, d);
  if (lane < 25) Ai[n*625 + lane*25 + w] += e / sum;
}

// ---------- epilogue: y[n][o][t][w] = sum_br (sum_v u[br][n][t*25+v][o]*Ai[br][v][w] + bd)
// then BN + residual + relu.  grid (64 t, 16 n), 256 thr (thread = o).
__global__ __launch_bounds__(256) void yep_k(const float* __restrict__ x,
    const float* __restrict__ Ai3, const __bf16* __restrict__ ubuf,
    const float* __restrict__ bd, const float* __restrict__ gamma,
    const float* __restrict__ beta, const float* __restrict__ bnm,
    const float* __restrict__ bnv, float* __restrict__ out){
  __shared__ float ais[3][25*28];
  int t = blockIdx.x, n = blockIdx.y, o = threadIdx.x;
  for (int l=o; l<1875; l+=256){
    int br = l/625, r = l%625;
    ais[br][(r/25)*28 + (r%25)] = Ai3[(br*NN + n)*625 + r];
  }
  __syncthreads();
  float y[25];
  #pragma unroll
  for (int w=0;w<25;++w) y[w]=0.f;
  for (int br=0; br<3; ++br){
    const __bf16* up = ubuf + ((size_t)(br*NN + n)*TV + t*25)*256 + o;
    float uv[25];
    #pragma unroll
    for (int v=0;v<25;++v) uv[v] = (float)up[(size_t)v*256];
    float bb = bd[br*256 + o];
    const float* ab = ais[br];
    for (int w=0; w<25; ++w){
      float a = bb;
      #pragma unroll
      for (int v=0;v<25;++v) a = fmaf(uv[v], ab[v*28+w], a);
      y[w] += a;
    }
  }
  float sc = gamma[o] * rsqrtf(bnv[o] + 1e-5f);
  float m  = bnm[o], be = beta[o];
  const float* xr = x + (size_t)n*CTV + (size_t)o*TV + t*25;
  float* orow = out + (size_t)n*CTV + (size_t)o*TV + t*25;
  #pragma unroll
  for (int w=0; w<25; ++w)
    orow[w] = fmaxf((y[w] - m)*sc + be + xr[w], 0.f);
}

extern "C" void kernel_launch(void* const* d_in, const int* in_sizes, int n_in,
                              void* d_out, int out_size, void* d_ws, size_t ws_size,
                              hipStream_t stream) {
  const float* x     = (const float*)d_in[0];
  const float* A     = (const float*)d_in[1];
  const float* PA    = (const float*)d_in[2];
  const float* wa    = (const float*)d_in[3];
  const float* ba    = (const float*)d_in[4];
  const float* wb    = (const float*)d_in[5];
  const float* bb    = (const float*)d_in[6];
  const float* wT1   = (const float*)d_in[7];
  const float* bT1   = (const float*)d_in[8];
  const float* wT2   = (const float*)d_in[9];
  const float* bT2   = (const float*)d_in[10];
  const float* wST11 = (const float*)d_in[11];
  const float* bST11 = (const float*)d_in[12];
  const float* wST12 = (const float*)d_in[13];
  const float* bST12 = (const float*)d_in[14];
  const float* wd    = (const float*)d_in[15];
  const float* bd    = (const float*)d_in[16];
  const float* gamma = (const float*)d_in[17];
  const float* beta  = (const float*)d_in[18];
  const float* bnm   = (const float*)d_in[19];
  const float* bnv   = (const float*)d_in[20];

  char* W = (char*)d_ws;
  float*  Aall = (float*)W;  W += 8192;
  float*  Ai3  = (float*)W;  W += 122880;    // 3*16*625 f32 (padded)
  __bf16* wab  = (__bf16*)W; W += 98304;     // 3*64*256 bf16
  __bf16* wbb  = (__bf16*)W; W += 98304;
  __bf16* wT1b = (__bf16*)W; W += 884736;    // 3*64*9*256 bf16
  __bf16* wT2b = (__bf16*)W; W += 884736;
  __bf16* wS1b = (__bf16*)W; W += 884736;
  __bf16* wS2b = (__bf16*)W; W += 884736;
  __bf16* wdb  = (__bf16*)W; W += 393216;    // 3*256*256 bf16
  __bf16* xt   = (__bf16*)W; W += 13107200;  // 16*1600*256 bf16
  // overlay region: part+fbuf live during attention; ubuf (39.3 MB) after
  char* R = W;
  float*  part = (float*)R;                  // 16*16*625 f32 (640 KB + pad)
  __bf16* fbuf = (__bf16*)(R + 655360);      // 2*16*64*1600 bf16 (6.55 MB)
  __bf16* ubuf = (__bf16*)R;                 // 3*16*1600*256 bf16 (39.3 MB)
  // total ws ~56.1 MB

  // prep
  xt_k<<<dim3(25,4,16), 256, 0, stream>>>(x, xt);
  wcvt_k<<<192, 256, 0, stream>>>(wa, wab, 49152);
  wcvt_k<<<192, 256, 0, stream>>>(wb, wbb, 49152);
  wcvt9_k<<<1728, 256, 0, stream>>>(wT1, wT1b);
  wcvt9_k<<<1728, 256, 0, stream>>>(wT2, wT2b);
  wcvt9_k<<<1728, 256, 0, stream>>>(wST11, wS1b);
  wcvt9_k<<<1728, 256, 0, stream>>>(wST12, wS2b);
  wcvt_k<<<768, 256, 0, stream>>>(wd, wdb, 196608);
  a_all_k<<<1, 128, 0, stream>>>(A, PA, Aall);
  init_ai3_k<<<118, 256, 0, stream>>>(Ai3, Aall);

  for (int i = 0; i < 3; ++i){
    bool even = (i % 2 == 0);
    float* Ai = Ai3 + i*(NN*625);
    // pair A: 1x1 convs
    conv_mfma_k<1,256><<<dim3(25,16), 512, 64*256*2, stream>>>(xt,
        wab + i*16384, wbb + i*16384, ba + i*64, bb + i*64, fbuf, 256, 0);
    scores2_k<<<dim3(16,16), 640, 0, stream>>>(fbuf, part);
    reduce2_k<<<dim3(16,25), 64, 0, stream>>>(part, Ai);
    // pair T: 9-tap convs
    conv_mfma_k<9,64><<<dim3(25,16), 512, 264*64*2, stream>>>(xt,
        wT1b + i*147456, wT2b + i*147456, bT1 + i*64, bT2 + i*64, fbuf, 2304, 0);
    scores2_k<<<dim3(16,16), 640, 0, stream>>>(fbuf, part);
    reduce2_k<<<dim3(16,25), 64, 0, stream>>>(part, Ai);
    // pair ST: even -> center tap (tapbase=4); odd -> full 9-tap
    if (even){
      conv_mfma_k<1,256><<<dim3(25,16), 512, 64*256*2, stream>>>(xt,
          wS1b + i*147456, wS2b + i*147456, bST11 + i*64, bST12 + i*64, fbuf, 2304, 4);
    } else {
      conv_mfma_k<9,64><<<dim3(25,16), 512, 264*64*2, stream>>>(xt,
          wS1b + i*147456, wS2b + i*147456, bST11 + i*64, bST12 + i*64, fbuf, 2304, 0);
    }
    scores2_k<<<dim3(16,16), 640, 0, stream>>>(fbuf, part);
    reduce2_k<<<dim3(16,25), 64, 0, stream>>>(part, Ai);
  }
  // u = wd*x for all branches (ubuf overlays part/fbuf — both dead now)
  ugemm_k<<<dim3(25,16,6), 512, 0, stream>>>(xt, wdb, ubuf);
  yep_k<<<dim3(64,16), 256, 0, stream>>>(x, Ai3, ubuf, bd, gamma, beta, bnm, bnv,
                                         (float*)d_out);
}

// Round 6
// 586.807 us; speedup vs baseline: 4.3798x; 1.2197x over previous
//
#include <hip/hip_runtime.h>
#include <hip/hip_bf16.h>

#define NN 16
#define CC 256
#define TT 64
#define VV 25
#define ICC 64
#define TV 1600      // TT*VV
#define CTV 409600   // CC*TV
#define ICTV 102400  // ICC*TV
#define NICTV 1638400

typedef __bf16 v8bf __attribute__((ext_vector_type(8)));
typedef __bf16 v4bf __attribute__((ext_vector_type(4)));
typedef float f32x16 __attribute__((ext_vector_type(16)));

struct ConvPairs {
  const __bf16* wA[5];
  const __bf16* wB[5];
  const float*  bA[5];
  const float*  bB[5];
  int wstride[5];
  int tapbase[5];
};

// ---------- x transpose to channels-last bf16: xt[n][p][c] = x[n][c][p]
__global__ __launch_bounds__(256) void xt_k(const float* __restrict__ x,
                                            __bf16* __restrict__ xt){
  __shared__ float tile[64][65];
  int p0 = blockIdx.x*64, c0 = blockIdx.y*64, n = blockIdx.z;
  int tid = threadIdx.x;
  for (int i = tid; i < 4096; i += 256){
    int cc = i >> 6, pp = i & 63;
    tile[cc][pp] = x[(size_t)n*CTV + (size_t)(c0+cc)*TV + p0 + pp];
  }
  __syncthreads();
  for (int i = tid; i < 4096; i += 256){
    int pp = i >> 6, cc = i & 63;
    xt[((size_t)n*TV + p0+pp)*256 + c0+cc] = (__bf16)tile[cc][pp];
  }
}

// ---------- 4 conv9 weight tensors [64*3][256][9] f32 -> [t][3][64][9][256] bf16
__global__ void wcvt9m_k(const float* __restrict__ i0, const float* __restrict__ i1,
                         const float* __restrict__ i2, const float* __restrict__ i3,
                         __bf16* __restrict__ out){
  int i = blockIdx.x*256 + threadIdx.x;
  if (i >= 4*442368) return;
  int t = i / 442368, j = i % 442368;
  const float* in = (t==0)?i0:(t==1)?i1:(t==2)?i2:i3;
  int c = j & 255;
  int k = (j >> 8) % 9;
  int r = j / 2304;            // s*64+o
  out[i] = (__bf16)in[(r*256 + c)*9 + k];
}

// ---------- wa+wb -> bf16 (contiguous out)
__global__ void wcvtab_k(const float* __restrict__ wa, const float* __restrict__ wb,
                         __bf16* __restrict__ out){
  int i = blockIdx.x*256 + threadIdx.x;
  if (i >= 2*49152) return;
  out[i] = (__bf16)((i < 49152) ? wa[i] : wb[i - 49152]);
}

__global__ void wcvt_k(const float* __restrict__ in, __bf16* __restrict__ out, int total){
  int i = blockIdx.x*256 + threadIdx.x;
  if (i < total) out[i] = (__bf16)in[i];
}

// ---------- static graph transform: A_all[s] = ch3 + softmax_col(ch4) + PA
__global__ void a_all_k(const float* __restrict__ A, const float* __restrict__ PA,
                        float* __restrict__ Aall){
  int t = threadIdx.x;
  if (t >= 75) return;
  int s = t / 25, w = t % 25;
  float a[25], m[25];
  float mx = -3.4e38f;
  for (int v = 0; v < 25; ++v){
    float av = A[(s*25 + v)*25 + w];
    a[v] = av;
    float d = (v == w) ? 1.f : 0.f;
    float mm = (8.f*av*av*av*av - 4.f*av*av - 4.f*av + d) * 0.04f;
    m[v] = mm;
    mx = fmaxf(mx, mm);
  }
  float sum = 0.f;
  for (int v = 0; v < 25; ++v){ float e = __expf(m[v]-mx); m[v] = e; sum += e; }
  float inv = 1.f/sum;
  for (int v = 0; v < 25; ++v){
    float av = a[v];
    float d = (v == w) ? 1.f : 0.f;
    Aall[(s*25+v)*25 + w] = m[v]*inv + 4.f*av*av - av - 2.f*d + PA[(s*25+v)*25+w];
  }
}

// ---------- MFMA conv mega: per pair z, fbuf[z*2+which][n][o][p] = conv + bias
template<int NTAPS, int CW>
__global__ __launch_bounds__(512) void conv_mfma_k(const __bf16* __restrict__ xt,
    ConvPairs cp, __bf16* __restrict__ fbuf){
  extern __shared__ __bf16 sm[];
  constexpr int NROWS = (NTAPS==9) ? 264 : 64;
  constexpr int HALO  = (NTAPS==9) ? 100 : 0;
  constexpr int GPR   = CW/8;
  constexpr int NCH   = 256/CW;
  int p0 = blockIdx.x*64;
  int n  = blockIdx.y;
  int pr = blockIdx.z;
  int tid = threadIdx.x;
  int lane = tid & 63;
  int wave = tid >> 6;
  int pq = wave & 1, oq = wave >> 1;
  int which = oq >> 1;
  int h = lane >> 5, l31 = lane & 31;
  const __bf16* wgt = which ? cp.wB[pr] : cp.wA[pr];
  const float* bias = which ? cp.bB[pr] : cp.bA[pr];
  int wstride = cp.wstride[pr];
  int tapbase = cp.tapbase[pr];
  int orow = (oq & 1)*32 + l31;
  const __bf16* xtn = xt + (size_t)n*CTV;

  f32x16 acc;
  #pragma unroll
  for (int r=0;r<16;++r) acc[r] = 0.f;

  for (int ch=0; ch<NCH; ++ch){
    for (int s2 = tid; s2 < NROWS*GPR; s2 += 512){
      int row = s2 / GPR, g = s2 % GPR;
      int pg = p0 - HALO + row;
      uint4 val = make_uint4(0u,0u,0u,0u);
      if ((unsigned)pg < 1600u)
        val = *(const uint4*)(xtn + (size_t)pg*256 + ch*CW + g*8);
      int gs = (g + row) & (GPR-1);
      *(uint4*)(sm + row*CW + gs*8) = val;
    }
    __syncthreads();
    const __bf16* wch = wgt + (size_t)orow*wstride + ch*CW;
    for (int tap=0; tap<NTAPS; ++tap){
      int rowbase = (NTAPS==9 ? tap*25 : 0) + pq*32;
      const __bf16* wr = wch + (size_t)(tapbase+tap)*256;
      #pragma unroll 4
      for (int ks=0; ks<CW/16; ++ks){
        v8bf a = *(const v8bf*)(wr + ks*16 + h*8);
        int row = rowbase + l31;
        int gs = ((ks*2 + h) + row) & (GPR-1);
        v8bf b = *(const v8bf*)(sm + row*CW + gs*8);
        acc = __builtin_amdgcn_mfma_f32_32x32x16_bf16(a, b, acc, 0, 0, 0);
      }
    }
    __syncthreads();
  }

  int p = p0 + pq*32 + l31;
  __bf16* out = fbuf + (size_t)(pr*2 + which)*NICTV + (size_t)n*ICTV + p;
  #pragma unroll
  for (int r=0; r<16; ++r){
    int ol = (r&3) + 8*(r>>2) + 4*h;
    int og = (oq&1)*32 + ol;
    out[(size_t)og*TV] = (__bf16)(acc[r] + bias[og]);
  }
}

// ---------- u GEMM: ubuf[br][n][p][o] = sum_c wd[br][o][c] * xt[n][p][c]
__global__ __launch_bounds__(512) void ugemm_k(const __bf16* __restrict__ xt,
    const __bf16* __restrict__ wdb, __bf16* __restrict__ ubuf){
  __shared__ __bf16 sm[64*256];
  int p0 = blockIdx.x*64;
  int n  = blockIdx.y;
  int br = blockIdx.z >> 1, half = blockIdx.z & 1;
  int tid = threadIdx.x;
  int lane = tid & 63;
  int wave = tid >> 6;
  int pq = wave & 1, oq = wave >> 1;
  int h = lane >> 5, l31 = lane & 31;
  const __bf16* xtn = xt + (size_t)n*CTV;

  f32x16 acc;
  #pragma unroll
  for (int r=0;r<16;++r) acc[r] = 0.f;

  for (int s2 = tid; s2 < 64*32; s2 += 512){
    int row = s2 >> 5, g = s2 & 31;
    uint4 val = *(const uint4*)(xtn + (size_t)(p0+row)*256 + g*8);
    int gs = (g + row) & 31;
    *(uint4*)(sm + row*256 + gs*8) = val;
  }
  __syncthreads();

  const __bf16* wr = wdb + ((size_t)br*256 + half*128 + oq*32 + l31)*256;
  #pragma unroll 4
  for (int ks=0; ks<16; ++ks){
    v8bf a = *(const v8bf*)(wr + ks*16 + h*8);
    int row = pq*32 + l31;
    int gs = ((ks*2 + h) + row) & 31;
    v8bf b = *(const v8bf*)(sm + row*256 + gs*8);
    acc = __builtin_amdgcn_mfma_f32_32x32x16_bf16(a, b, acc, 0, 0, 0);
  }

  int p = p0 + pq*32 + l31;
  __bf16* out = ubuf + ((size_t)(br*NN + n)*TV + p)*256;
  #pragma unroll
  for (int g=0; g<4; ++g){
    int og0 = half*128 + oq*32 + 8*g + 4*h;
    v4bf pk;
    pk[0] = (__bf16)acc[4*g+0];
    pk[1] = (__bf16)acc[4*g+1];
    pk[2] = (__bf16)acc[4*g+2];
    pk[3] = (__bf16)acc[4*g+3];
    *(v4bf*)(out + og0) = pk;
  }
}

// ---------- scores mega: grid (16 chunk, 16 n, P pairs)
__global__ __launch_bounds__(640) void scores2_k(const __bf16* __restrict__ fbuf,
                                                 float* __restrict__ part, int pairbase){
  __shared__ float s1[64*26];
  __shared__ float s2[64*26];
  int chunk = blockIdx.x, n = blockIdx.y, pr = blockIdx.z;
  int tid = threadIdx.x;
  const __bf16* f1 = fbuf + (size_t)(pr*2)*NICTV   + (size_t)n*ICTV;
  const __bf16* f2 = fbuf + (size_t)(pr*2+1)*NICTV + (size_t)n*ICTV;
  int v = tid/25, w = tid%25;
  float acc = 0.f;
  for (int sub=0; sub<4; ++sub){
    int q0 = chunk*256 + sub*64;
    for (int l=tid; l<1600; l+=640){
      int qq = l/25, vv = l%25;
      s1[qq*26+vv] = (float)f1[(q0+qq)*25+vv];
      s2[qq*26+vv] = (float)f2[(q0+qq)*25+vv];
    }
    __syncthreads();
    if (tid < 625){
      #pragma unroll 8
      for (int q=0;q<64;++q) acc = fmaf(s1[q*26+v], s2[q*26+w], acc);
    }
    __syncthreads();
  }
  if (tid < 625) part[(((size_t)(pairbase+pr)*NN + n)*16 + chunk)*625 + tid] = acc;
}

// ---------- reduce all 9 pairs: softmax each, sum into branches, Ai3 = Aall + sums
// grid (16 n, 25 w), block 64 (lane = v)
__global__ __launch_bounds__(64) void reduce_all_k(const float* __restrict__ part,
    const float* __restrict__ Aall, float* __restrict__ Ai3){
  const int pairbr[9] = {0,1,2,0,2, 0,1,2,1};
  int n = blockIdx.x, w = blockIdx.y;
  int lane = threadIdx.x;
  float accbr[3] = {0.f, 0.f, 0.f};
  for (int pr=0; pr<9; ++pr){
    float s = 0.f;
    if (lane < 25){
      const float* pp = part + (((size_t)pr*NN + n)*16)*625 + lane*25 + w;
      #pragma unroll
      for (int ch=0; ch<16; ++ch) s += pp[ch*625];
    }
    s *= (1.f/4096.f);
    float mval = (lane<25) ? s : -3.4e38f;
    #pragma unroll
    for (int d=32; d>0; d>>=1) mval = fmaxf(mval, __shfl_xor(mval, d));
    float e = (lane<25) ? __expf(s - mval) : 0.f;
    float sum = e;
    #pragma unroll
    for (int d=32; d>0; d>>=1) sum += __shfl_xor(sum, d);
    accbr[pairbr[pr]] += e / sum;
  }
  if (lane < 25){
    #pragma unroll
    for (int br=0; br<3; ++br)
      Ai3[((size_t)br*NN + n)*625 + lane*25 + w] =
        Aall[br*625 + lane*25 + w] + accbr[br];
  }
}

// ---------- epilogue: y + BN + residual + relu
__global__ __launch_bounds__(256) void yep_k(const float* __restrict__ x,
    const float* __restrict__ Ai3, const __bf16* __restrict__ ubuf,
    const float* __restrict__ bd, const float* __restrict__ gamma,
    const float* __restrict__ beta, const float* __restrict__ bnm,
    const float* __restrict__ bnv, float* __restrict__ out){
  __shared__ float ais[3][25*28];
  int t = blockIdx.x, n = blockIdx.y, o = threadIdx.x;
  for (int l=o; l<1875; l+=256){
    int br = l/625, r = l%625;
    ais[br][(r/25)*28 + (r%25)] = Ai3[((size_t)br*NN + n)*625 + r];
  }
  __syncthreads();
  float y[25];
  #pragma unroll
  for (int w=0;w<25;++w) y[w]=0.f;
  for (int br=0; br<3; ++br){
    const __bf16* up = ubuf + ((size_t)(br*NN + n)*TV + t*25)*256 + o;
    float uv[25];
    #pragma unroll
    for (int v=0;v<25;++v) uv[v] = (float)up[(size_t)v*256];
    float bb = bd[br*256 + o];
    const float* ab = ais[br];
    for (int w=0; w<25; ++w){
      float a = bb;
      #pragma unroll
      for (int v=0;v<25;++v) a = fmaf(uv[v], ab[v*28+w], a);
      y[w] += a;
    }
  }
  float sc = gamma[o] * rsqrtf(bnv[o] + 1e-5f);
  float m  = bnm[o], be = beta[o];
  const float* xr = x + (size_t)n*CTV + (size_t)o*TV + t*25;
  float* orow = out + (size_t)n*CTV + (size_t)o*TV + t*25;
  #pragma unroll
  for (int w=0; w<25; ++w)
    orow[w] = fmaxf((y[w] - m)*sc + be + xr[w], 0.f);
}

extern "C" void kernel_launch(void* const* d_in, const int* in_sizes, int n_in,
                              void* d_out, int out_size, void* d_ws, size_t ws_size,
                              hipStream_t stream) {
  const float* x     = (const float*)d_in[0];
  const float* A     = (const float*)d_in[1];
  const float* PA    = (const float*)d_in[2];
  const float* wa    = (const float*)d_in[3];
  const float* ba    = (const float*)d_in[4];
  const float* wb    = (const float*)d_in[5];
  const float* bb    = (const float*)d_in[6];
  const float* wT1   = (const float*)d_in[7];
  const float* bT1   = (const float*)d_in[8];
  const float* wT2   = (const float*)d_in[9];
  const float* bT2   = (const float*)d_in[10];
  const float* wST11 = (const float*)d_in[11];
  const float* bST11 = (const float*)d_in[12];
  const float* wST12 = (const float*)d_in[13];
  const float* bST12 = (const float*)d_in[14];
  const float* wd    = (const float*)d_in[15];
  const float* bd    = (const float*)d_in[16];
  const float* gamma = (const float*)d_in[17];
  const float* beta  = (const float*)d_in[18];
  const float* bnm   = (const float*)d_in[19];
  const float* bnv   = (const float*)d_in[20];

  char* W = (char*)d_ws;
  float*  Aall = (float*)W;  W += 8192;
  float*  Ai3  = (float*)W;  W += 122880;    // 3*16*625 f32 (padded)
  __bf16* wab  = (__bf16*)W; W += 98304;     // 3*64*256 bf16
  __bf16* wbb  = (__bf16*)W; W += 98304;
  __bf16* wT1b = (__bf16*)W; W += 884736;    // 3*64*9*256 bf16 x4 contiguous
  __bf16* wT2b = (__bf16*)W; W += 884736;
  __bf16* wS1b = (__bf16*)W; W += 884736;
  __bf16* wS2b = (__bf16*)W; W += 884736;
  __bf16* wdb  = (__bf16*)W; W += 393216;    // 3*256*256 bf16
  __bf16* xt   = (__bf16*)W; W += 13107200;  // 16*1600*256 bf16
  char* R = W;               W += 39321600;  // fbuf (10 slices, 32.8MB) / ubuf (39.3MB)
  float*  part = (float*)W;  W += 23040000;  // 9*16*16*625 f32
  __bf16* fbuf = (__bf16*)R;
  __bf16* ubuf = (__bf16*)R;
  // total ws ~62.7 MB

  // prep
  xt_k<<<dim3(25,4,16), 256, 0, stream>>>(x, xt);
  wcvt9m_k<<<(4*442368+255)/256, 256, 0, stream>>>(wT1, wT2, wST11, wST12, wT1b);
  wcvtab_k<<<(2*49152+255)/256, 256, 0, stream>>>(wa, wb, wab);
  wcvt_k<<<768, 256, 0, stream>>>(wd, wdb, 196608);
  a_all_k<<<1, 128, 0, stream>>>(A, PA, Aall);

  // phase 1: all "1x1" pairs (A x3, ST even x2) -> fbuf slices 0..9, part pairs 0..4
  {
    ConvPairs cp;
    for (int i=0;i<3;++i){
      cp.wA[i] = wab + i*16384;  cp.wB[i] = wbb + i*16384;
      cp.bA[i] = ba + i*64;      cp.bB[i] = bb + i*64;
      cp.wstride[i] = 256;       cp.tapbase[i] = 0;
    }
    // ST pairs for even branches 0,2: center tap of 9-tap weights
    int evens[2] = {0, 2};
    for (int j=0;j<2;++j){
      int i = evens[j];
      cp.wA[3+j] = wS1b + i*147456;  cp.wB[3+j] = wS2b + i*147456;
      cp.bA[3+j] = bST11 + i*64;     cp.bB[3+j] = bST12 + i*64;
      cp.wstride[3+j] = 2304;        cp.tapbase[3+j] = 4;
    }
    conv_mfma_k<1,256><<<dim3(25,16,5), 512, 64*256*2, stream>>>(xt, cp, fbuf);
    scores2_k<<<dim3(16,16,5), 640, 0, stream>>>(fbuf, part, 0);
  }

  // phase 2: all 9-tap pairs (T x3, ST odd x1) -> fbuf slices 0..7, part pairs 5..8
  {
    ConvPairs cp;
    for (int i=0;i<3;++i){
      cp.wA[i] = wT1b + i*147456;  cp.wB[i] = wT2b + i*147456;
      cp.bA[i] = bT1 + i*64;       cp.bB[i] = bT2 + i*64;
      cp.wstride[i] = 2304;        cp.tapbase[i] = 0;
    }
    cp.wA[3] = wS1b + 1*147456;  cp.wB[3] = wS2b + 1*147456;
    cp.bA[3] = bST11 + 1*64;     cp.bB[3] = bST12 + 1*64;
    cp.wstride[3] = 2304;        cp.tapbase[3] = 0;
    cp.wA[4] = cp.wA[3]; cp.wB[4] = cp.wB[3]; cp.bA[4] = cp.bA[3]; cp.bB[4] = cp.bB[3];
    cp.wstride[4] = 2304; cp.tapbase[4] = 0;
    conv_mfma_k<9,64><<<dim3(25,16,4), 512, 264*64*2, stream>>>(xt, cp, fbuf);
    scores2_k<<<dim3(16,16,4), 640, 0, stream>>>(fbuf, part, 5);
  }

  // u GEMM (overwrites fbuf region — fbuf dead after phase-2 scores)
  ugemm_k<<<dim3(25,16,6), 512, 0, stream>>>(xt, wdb, ubuf);
  // all-pair softmax reduce -> Ai3
  reduce_all_k<<<dim3(16,25), 64, 0, stream>>>(part, Aall, Ai3);
  // epilogue
  yep_k<<<dim3(64,16), 256, 0, stream>>>(x, Ai3, ubuf, bd, gamma, beta, bnm, bnv,
                                         (float*)d_out);
}

// Round 7
// 493.942 us; speedup vs baseline: 5.2032x; 1.1880x over previous
//
#include <hip/hip_runtime.h>
#include <hip/hip_bf16.h>

#define NN 16
#define CC 256
#define TT 64
#define VV 25
#define ICC 64
#define TV 1600      // TT*VV
#define CTV 409600   // CC*TV
#define ICTV 102400  // ICC*TV
#define NICTV 1638400

typedef __bf16 v8bf __attribute__((ext_vector_type(8)));
typedef __bf16 v4bf __attribute__((ext_vector_type(4)));
typedef float f32x16 __attribute__((ext_vector_type(16)));

struct ConvPairs {
  const __bf16* wA[5];
  const __bf16* wB[5];
  const float*  bA[5];
  const float*  bB[5];
};

// ---------- x transpose to channels-last bf16: xt[n][p][c] = x[n][c][p]
__global__ __launch_bounds__(256) void xt_k(const float* __restrict__ x,
                                            __bf16* __restrict__ xt){
  __shared__ float tile[64][65];
  int p0 = blockIdx.x*64, c0 = blockIdx.y*64, n = blockIdx.z;
  int tid = threadIdx.x;
  for (int i = tid; i < 4096; i += 256){
    int cc = i >> 6, pp = i & 63;
    tile[cc][pp] = x[(size_t)n*CTV + (size_t)(c0+cc)*TV + p0 + pp];
  }
  __syncthreads();
  for (int i = tid; i < 4096; i += 256){
    int pp = i >> 6, cc = i & 63;
    xt[((size_t)n*TV + p0+pp)*256 + c0+cc] = (__bf16)tile[cc][pp];
  }
}

// ---------- 4 conv9 weight tensors [64*3][256][9] f32 -> [t][3][64][9][256] bf16
__global__ void wcvt9m_k(const float* __restrict__ i0, const float* __restrict__ i1,
                         const float* __restrict__ i2, const float* __restrict__ i3,
                         __bf16* __restrict__ out){
  int i = blockIdx.x*256 + threadIdx.x;
  if (i >= 4*442368) return;
  int t = i / 442368, j = i % 442368;
  const float* in = (t==0)?i0:(t==1)?i1:(t==2)?i2:i3;
  int c = j & 255;
  int k = (j >> 8) % 9;
  int r = j / 2304;            // s*64+o
  out[i] = (__bf16)in[(r*256 + c)*9 + k];
}

// ---------- center-tap compact: wST [s*64+o][256][9] f32 -> [s][o][256] bf16 (tap 4)
__global__ void wcvtc_k(const float* __restrict__ w1, const float* __restrict__ w2,
                        __bf16* __restrict__ o1, __bf16* __restrict__ o2){
  int i = blockIdx.x*256 + threadIdx.x;
  if (i >= 49152) return;
  o1[i] = (__bf16)w1[i*9 + 4];
  o2[i] = (__bf16)w2[i*9 + 4];
}

// ---------- wa+wb -> bf16 (contiguous out)
__global__ void wcvtab_k(const float* __restrict__ wa, const float* __restrict__ wb,
                         __bf16* __restrict__ out){
  int i = blockIdx.x*256 + threadIdx.x;
  if (i >= 2*49152) return;
  out[i] = (__bf16)((i < 49152) ? wa[i] : wb[i - 49152]);
}

__global__ void wcvt_k(const float* __restrict__ in, __bf16* __restrict__ out, int total){
  int i = blockIdx.x*256 + threadIdx.x;
  if (i < total) out[i] = (__bf16)in[i];
}

// ---------- static graph transform: A_all[s] = ch3 + softmax_col(ch4) + PA
__global__ void a_all_k(const float* __restrict__ A, const float* __restrict__ PA,
                        float* __restrict__ Aall){
  int t = threadIdx.x;
  if (t >= 75) return;
  int s = t / 25, w = t % 25;
  float a[25], m[25];
  float mx = -3.4e38f;
  for (int v = 0; v < 25; ++v){
    float av = A[(s*25 + v)*25 + w];
    a[v] = av;
    float d = (v == w) ? 1.f : 0.f;
    float mm = (8.f*av*av*av*av - 4.f*av*av - 4.f*av + d) * 0.04f;
    m[v] = mm;
    mx = fmaxf(mx, mm);
  }
  float sum = 0.f;
  for (int v = 0; v < 25; ++v){ float e = __expf(m[v]-mx); m[v] = e; sum += e; }
  float inv = 1.f/sum;
  for (int v = 0; v < 25; ++v){
    float av = a[v];
    float d = (v == w) ? 1.f : 0.f;
    Aall[(s*25+v)*25 + w] = m[v]*inv + 4.f*av*av - av - 2.f*d + PA[(s*25+v)*25+w];
  }
}

// ---------- MFMA conv v2: 2x2 quad tiles per wave (64o x 64p), compile-time K-loop
// grid (13 ptile, 16 n, NP pairs), block 256 (4 waves = 2 which x 2 p-half)
template<int NTAPS, int CW, int WSTRIDE, int TAPBASE, int MINW>
__global__ __launch_bounds__(256, MINW) void conv2_k(const __bf16* __restrict__ xt,
    ConvPairs cp, __bf16* __restrict__ fbuf){
  extern __shared__ __bf16 sm[];
  constexpr int HALO  = (NTAPS==9) ? 100 : 0;
  constexpr int NROWS = 128 + 2*HALO;
  constexpr int GPR   = CW/8;            // 16B groups per LDS row
  constexpr int NCH   = 256/CW;
  int p0 = blockIdx.x*128;
  int n  = blockIdx.y;
  int pr = blockIdx.z;
  int tid = threadIdx.x;
  int lane = tid & 63;
  int wave = tid >> 6;
  int which = wave >> 1, ph = wave & 1;
  int h = lane >> 5, l31 = lane & 31;
  const __bf16* wgt = which ? cp.wB[pr] : cp.wA[pr];
  const float* bias = which ? cp.bB[pr] : cp.bA[pr];
  const __bf16* xtn = xt + (size_t)n*CTV;
  // lane-fixed weight base for o-quad 0 (row l31); o-quad 1 adds 32*WSTRIDE
  const __bf16* wl = wgt + (size_t)l31*WSTRIDE + TAPBASE*256 + h*8;

  f32x16 acc[2][2];   // [oq][pq]
  #pragma unroll
  for (int a=0;a<2;++a)
    #pragma unroll
    for (int b=0;b<2;++b)
      #pragma unroll
      for (int r=0;r<16;++r) acc[a][b][r] = 0.f;

  for (int ch=0; ch<NCH; ++ch){
    // stage slab chunk: NROWS x CW bf16, group-swizzled
    for (int s2 = tid; s2 < NROWS*GPR; s2 += 256){
      int row = s2 / GPR, g = s2 % GPR;
      int pg = p0 - HALO + row;
      uint4 val = make_uint4(0u,0u,0u,0u);
      if ((unsigned)pg < 1600u)
        val = *(const uint4*)(xtn + (size_t)pg*256 + ch*CW + g*8);
      int gs = (g + row) & (GPR-1);
      *(uint4*)(sm + row*CW + gs*8) = val;
    }
    __syncthreads();
    const __bf16* wc = wl + ch*CW;
    #pragma unroll
    for (int tap=0; tap<NTAPS; ++tap){
      int rowb = (NTAPS==9 ? tap*25 : 0) + HALO + ph*64 - HALO + l31;
      // rowb simplifies to tap*25 + ph*64 + l31 (slab row for pq=0)
      #pragma unroll
      for (int ks=0; ks<CW/16; ++ks){
        v8bf a0 = *(const v8bf*)(wc + tap*256 + ks*16);
        v8bf a1 = *(const v8bf*)(wc + (size_t)32*WSTRIDE + tap*256 + ks*16);
        int r0 = rowb;
        int g0 = ((ks*2 + h) + r0) & (GPR-1);
        v8bf b0 = *(const v8bf*)(sm + r0*CW + g0*8);
        int r1 = rowb + 32;
        int g1 = ((ks*2 + h) + r1) & (GPR-1);
        v8bf b1 = *(const v8bf*)(sm + r1*CW + g1*8);
        acc[0][0] = __builtin_amdgcn_mfma_f32_32x32x16_bf16(a0, b0, acc[0][0], 0,0,0);
        acc[1][0] = __builtin_amdgcn_mfma_f32_32x32x16_bf16(a1, b0, acc[1][0], 0,0,0);
        acc[0][1] = __builtin_amdgcn_mfma_f32_32x32x16_bf16(a0, b1, acc[0][1], 0,0,0);
        acc[1][1] = __builtin_amdgcn_mfma_f32_32x32x16_bf16(a1, b1, acc[1][1], 0,0,0);
      }
    }
    __syncthreads();
  }

  // epilogue: D col = l31 -> p, row = (r&3)+8*(r>>2)+4*h -> o
  __bf16* outb = fbuf + (size_t)(pr*2 + which)*NICTV + (size_t)n*ICTV;
  #pragma unroll
  for (int pq=0; pq<2; ++pq){
    int p = p0 + ph*64 + pq*32 + l31;
    if (p >= 1600) continue;
    #pragma unroll
    for (int oq=0; oq<2; ++oq){
      #pragma unroll
      for (int r=0; r<16; ++r){
        int og = oq*32 + (r&3) + 8*(r>>2) + 4*h;
        outb[(size_t)og*TV + p] = (__bf16)(acc[oq][pq][r] + bias[og]);
      }
    }
  }
}

// ---------- u GEMM: ubuf[br][n][p][o] = sum_c wd[br][o][c] * xt[n][p][c]
__global__ __launch_bounds__(512) void ugemm_k(const __bf16* __restrict__ xt,
    const __bf16* __restrict__ wdb, __bf16* __restrict__ ubuf){
  __shared__ __bf16 sm[64*256];
  int p0 = blockIdx.x*64;
  int n  = blockIdx.y;
  int br = blockIdx.z >> 1, half = blockIdx.z & 1;
  int tid = threadIdx.x;
  int lane = tid & 63;
  int wave = tid >> 6;
  int pq = wave & 1, oq = wave >> 1;
  int h = lane >> 5, l31 = lane & 31;
  const __bf16* xtn = xt + (size_t)n*CTV;

  f32x16 acc;
  #pragma unroll
  for (int r=0;r<16;++r) acc[r] = 0.f;

  for (int s2 = tid; s2 < 64*32; s2 += 512){
    int row = s2 >> 5, g = s2 & 31;
    uint4 val = *(const uint4*)(xtn + (size_t)(p0+row)*256 + g*8);
    int gs = (g + row) & 31;
    *(uint4*)(sm + row*256 + gs*8) = val;
  }
  __syncthreads();

  const __bf16* wr = wdb + ((size_t)br*256 + half*128 + oq*32 + l31)*256;
  #pragma unroll 4
  for (int ks=0; ks<16; ++ks){
    v8bf a = *(const v8bf*)(wr + ks*16 + h*8);
    int row = pq*32 + l31;
    int gs = ((ks*2 + h) + row) & 31;
    v8bf b = *(const v8bf*)(sm + row*256 + gs*8);
    acc = __builtin_amdgcn_mfma_f32_32x32x16_bf16(a, b, acc, 0, 0, 0);
  }

  int p = p0 + pq*32 + l31;
  __bf16* out = ubuf + ((size_t)(br*NN + n)*TV + p)*256;
  #pragma unroll
  for (int g=0; g<4; ++g){
    int og0 = half*128 + oq*32 + 8*g + 4*h;
    v4bf pk;
    pk[0] = (__bf16)acc[4*g+0];
    pk[1] = (__bf16)acc[4*g+1];
    pk[2] = (__bf16)acc[4*g+2];
    pk[3] = (__bf16)acc[4*g+3];
    *(v4bf*)(out + og0) = pk;
  }
}

// ---------- scores mega: grid (16 chunk, 16 n, P pairs)
__global__ __launch_bounds__(640) void scores2_k(const __bf16* __restrict__ fbuf,
                                                 float* __restrict__ part, int pairbase){
  __shared__ float s1[64*26];
  __shared__ float s2[64*26];
  int chunk = blockIdx.x, n = blockIdx.y, pr = blockIdx.z;
  int tid = threadIdx.x;
  const __bf16* f1 = fbuf + (size_t)(pr*2)*NICTV   + (size_t)n*ICTV;
  const __bf16* f2 = fbuf + (size_t)(pr*2+1)*NICTV + (size_t)n*ICTV;
  int v = tid/25, w = tid%25;
  float acc = 0.f;
  for (int sub=0; sub<4; ++sub){
    int q0 = chunk*256 + sub*64;
    for (int l=tid; l<1600; l+=640){
      int qq = l/25, vv = l%25;
      s1[qq*26+vv] = (float)f1[(q0+qq)*25+vv];
      s2[qq*26+vv] = (float)f2[(q0+qq)*25+vv];
    }
    __syncthreads();
    if (tid < 625){
      #pragma unroll 8
      for (int q=0;q<64;++q) acc = fmaf(s1[q*26+v], s2[q*26+w], acc);
    }
    __syncthreads();
  }
  if (tid < 625) part[(((size_t)(pairbase+pr)*NN + n)*16 + chunk)*625 + tid] = acc;
}

// ---------- reduce all 9 pairs: softmax each, sum into branches, Ai3 = Aall + sums
__global__ __launch_bounds__(64) void reduce_all_k(const float* __restrict__ part,
    const float* __restrict__ Aall, float* __restrict__ Ai3){
  const int pairbr[9] = {0,1,2,0,2, 0,1,2,1};
  int n = blockIdx.x, w = blockIdx.y;
  int lane = threadIdx.x;
  float accbr[3] = {0.f, 0.f, 0.f};
  for (int pr=0; pr<9; ++pr){
    float s = 0.f;
    if (lane < 25){
      const float* pp = part + (((size_t)pr*NN + n)*16)*625 + lane*25 + w;
      #pragma unroll
      for (int ch=0; ch<16; ++ch) s += pp[ch*625];
    }
    s *= (1.f/4096.f);
    float mval = (lane<25) ? s : -3.4e38f;
    #pragma unroll
    for (int d=32; d>0; d>>=1) mval = fmaxf(mval, __shfl_xor(mval, d));
    float e = (lane<25) ? __expf(s - mval) : 0.f;
    float sum = e;
    #pragma unroll
    for (int d=32; d>0; d>>=1) sum += __shfl_xor(sum, d);
    accbr[pairbr[pr]] += e / sum;
  }
  if (lane < 25){
    #pragma unroll
    for (int br=0; br<3; ++br)
      Ai3[((size_t)br*NN + n)*625 + lane*25 + w] =
        Aall[br*625 + lane*25 + w] + accbr[br];
  }
}

// ---------- epilogue: y + BN + residual + relu
__global__ __launch_bounds__(256) void yep_k(const float* __restrict__ x,
    const float* __restrict__ Ai3, const __bf16* __restrict__ ubuf,
    const float* __restrict__ bd, const float* __restrict__ gamma,
    const float* __restrict__ beta, const float* __restrict__ bnm,
    const float* __restrict__ bnv, float* __restrict__ out){
  __shared__ float ais[3][25*28];
  int t = blockIdx.x, n = blockIdx.y, o = threadIdx.x;
  for (int l=o; l<1875; l+=256){
    int br = l/625, r = l%625;
    ais[br][(r/25)*28 + (r%25)] = Ai3[((size_t)br*NN + n)*625 + r];
  }
  __syncthreads();
  float y[25];
  #pragma unroll
  for (int w=0;w<25;++w) y[w]=0.f;
  for (int br=0; br<3; ++br){
    const __bf16* up = ubuf + ((size_t)(br*NN + n)*TV + t*25)*256 + o;
    float uv[25];
    #pragma unroll
    for (int v=0;v<25;++v) uv[v] = (float)up[(size_t)v*256];
    float bb = bd[br*256 + o];
    const float* ab = ais[br];
    for (int w=0; w<25; ++w){
      float a = bb;
      #pragma unroll
      for (int v=0;v<25;++v) a = fmaf(uv[v], ab[v*28+w], a);
      y[w] += a;
    }
  }
  float sc = gamma[o] * rsqrtf(bnv[o] + 1e-5f);
  float m  = bnm[o], be = beta[o];
  const float* xr = x + (size_t)n*CTV + (size_t)o*TV + t*25;
  float* orow = out + (size_t)n*CTV + (size_t)o*TV + t*25;
  #pragma unroll
  for (int w=0; w<25; ++w)
    orow[w] = fmaxf((y[w] - m)*sc + be + xr[w], 0.f);
}

extern "C" void kernel_launch(void* const* d_in, const int* in_sizes, int n_in,
                              void* d_out, int out_size, void* d_ws, size_t ws_size,
                              hipStream_t stream) {
  const float* x     = (const float*)d_in[0];
  const float* A     = (const float*)d_in[1];
  const float* PA    = (const float*)d_in[2];
  const float* wa    = (const float*)d_in[3];
  const float* ba    = (const float*)d_in[4];
  const float* wb    = (const float*)d_in[5];
  const float* bb    = (const float*)d_in[6];
  const float* wT1   = (const float*)d_in[7];
  const float* bT1   = (const float*)d_in[8];
  const float* wT2   = (const float*)d_in[9];
  const float* bT2   = (const float*)d_in[10];
  const float* wST11 = (const float*)d_in[11];
  const float* bST11 = (const float*)d_in[12];
  const float* wST12 = (const float*)d_in[13];
  const float* bST12 = (const float*)d_in[14];
  const float* wd    = (const float*)d_in[15];
  const float* bd    = (const float*)d_in[16];
  const float* gamma = (const float*)d_in[17];
  const float* beta  = (const float*)d_in[18];
  const float* bnm   = (const float*)d_in[19];
  const float* bnv   = (const float*)d_in[20];

  char* W = (char*)d_ws;
  float*  Aall = (float*)W;  W += 8192;
  float*  Ai3  = (float*)W;  W += 122880;    // 3*16*625 f32 (padded)
  __bf16* wab  = (__bf16*)W; W += 98304;     // 3*64*256 bf16
  __bf16* wbb  = (__bf16*)W; W += 98304;
  __bf16* wT1b = (__bf16*)W; W += 884736;    // 3*64*9*256 bf16 x4 contiguous
  __bf16* wT2b = (__bf16*)W; W += 884736;
  __bf16* wS1b = (__bf16*)W; W += 884736;
  __bf16* wS2b = (__bf16*)W; W += 884736;
  __bf16* wS1c = (__bf16*)W; W += 98304;     // center-tap compact [3][64][256]
  __bf16* wS2c = (__bf16*)W; W += 98304;
  __bf16* wdb  = (__bf16*)W; W += 393216;    // 3*256*256 bf16
  __bf16* xt   = (__bf16*)W; W += 13107200;  // 16*1600*256 bf16
  char* R = W;               W += 39321600;  // fbuf (10 slices, 32.8MB) / ubuf (39.3MB)
  float*  part = (float*)W;  W += 23040000;  // 9*16*16*625 f32
  __bf16* fbuf = (__bf16*)R;
  __bf16* ubuf = (__bf16*)R;
  // total ws ~62.9 MB

  // prep
  xt_k<<<dim3(25,4,16), 256, 0, stream>>>(x, xt);
  wcvt9m_k<<<(4*442368+255)/256, 256, 0, stream>>>(wT1, wT2, wST11, wST12, wT1b);
  wcvtc_k<<<192, 256, 0, stream>>>(wST11, wST12, wS1c, wS2c);
  wcvtab_k<<<(2*49152+255)/256, 256, 0, stream>>>(wa, wb, wab);
  wcvt_k<<<768, 256, 0, stream>>>(wd, wdb, 196608);
  a_all_k<<<1, 128, 0, stream>>>(A, PA, Aall);

  // phase 1: all "1x1" pairs (A x3, ST-even x2 via compact center-tap) -> pairs 0..4
  {
    ConvPairs cp;
    for (int i=0;i<3;++i){
      cp.wA[i] = wab + i*16384;  cp.wB[i] = wbb + i*16384;
      cp.bA[i] = ba + i*64;      cp.bB[i] = bb + i*64;
    }
    int evens[2] = {0, 2};
    for (int j=0;j<2;++j){
      int i = evens[j];
      cp.wA[3+j] = wS1c + i*16384;  cp.wB[3+j] = wS2c + i*16384;
      cp.bA[3+j] = bST11 + i*64;    cp.bB[3+j] = bST12 + i*64;
    }
    conv2_k<1,128,256,0,4><<<dim3(13,16,5), 256, 128*128*2, stream>>>(xt, cp, fbuf);
    scores2_k<<<dim3(16,16,5), 640, 0, stream>>>(fbuf, part, 0);
  }

  // phase 2: all 9-tap pairs (T x3, ST-odd x1) -> pairs 5..8
  {
    ConvPairs cp;
    for (int i=0;i<3;++i){
      cp.wA[i] = wT1b + i*147456;  cp.wB[i] = wT2b + i*147456;
      cp.bA[i] = bT1 + i*64;       cp.bB[i] = bT2 + i*64;
    }
    cp.wA[3] = wS1b + 1*147456;  cp.wB[3] = wS2b + 1*147456;
    cp.bA[3] = bST11 + 1*64;     cp.bB[3] = bST12 + 1*64;
    cp.wA[4] = cp.wA[3]; cp.wB[4] = cp.wB[3]; cp.bA[4] = cp.bA[3]; cp.bB[4] = cp.bB[3];
    conv2_k<9,64,2304,0,3><<<dim3(13,16,4), 256, 328*64*2, stream>>>(xt, cp, fbuf);
    scores2_k<<<dim3(16,16,4), 640, 0, stream>>>(fbuf, part, 5);
  }

  // u GEMM (overwrites fbuf region — fbuf dead after phase-2 scores)
  ugemm_k<<<dim3(25,16,6), 512, 0, stream>>>(xt, wdb, ubuf);
  // all-pair softmax reduce -> Ai3
  reduce_all_k<<<dim3(16,25), 64, 0, stream>>>(part, Aall, Ai3);
  // epilogue
  yep_k<<<dim3(64,16), 256, 0, stream>>>(x, Ai3, ubuf, bd, gamma, beta, bnm, bnv,
                                         (float*)d_out);
}

// Round 8
// 417.211 us; speedup vs baseline: 6.1602x; 1.1839x over previous
//
#include <hip/hip_runtime.h>
#include <hip/hip_bf16.h>

#define NN 16
#define CC 256
#define TT 64
#define VV 25
#define ICC 64
#define TV 1600      // TT*VV
#define CTV 409600   // CC*TV
#define ICTV 102400  // ICC*TV
#define NICTV 1638400

typedef __bf16 v8bf __attribute__((ext_vector_type(8)));
typedef __bf16 v4bf __attribute__((ext_vector_type(4)));
typedef float f32x16 __attribute__((ext_vector_type(16)));

struct ConvPairs {
  const __bf16* wA[5];
  const __bf16* wB[5];
  const float*  bA[5];
  const float*  bB[5];
};

// ---------- x transpose to channels-last bf16: xt[n][p][c] = x[n][c][p]
__global__ __launch_bounds__(256) void xt_k(const float* __restrict__ x,
                                            __bf16* __restrict__ xt){
  __shared__ float tile[64][65];
  int p0 = blockIdx.x*64, c0 = blockIdx.y*64, n = blockIdx.z;
  int tid = threadIdx.x;
  for (int i = tid; i < 4096; i += 256){
    int cc = i >> 6, pp = i & 63;
    tile[cc][pp] = x[(size_t)n*CTV + (size_t)(c0+cc)*TV + p0 + pp];
  }
  __syncthreads();
  for (int i = tid; i < 4096; i += 256){
    int pp = i >> 6, cc = i & 63;
    xt[((size_t)n*TV + p0+pp)*256 + c0+cc] = (__bf16)tile[cc][pp];
  }
}

// ---------- 4 conv9 weight tensors [64*3][256][9] f32 -> [t][3][64][9][256] bf16
__global__ void wcvt9m_k(const float* __restrict__ i0, const float* __restrict__ i1,
                         const float* __restrict__ i2, const float* __restrict__ i3,
                         __bf16* __restrict__ out){
  int i = blockIdx.x*256 + threadIdx.x;
  if (i >= 4*442368) return;
  int t = i / 442368, j = i % 442368;
  const float* in = (t==0)?i0:(t==1)?i1:(t==2)?i2:i3;
  int c = j & 255;
  int k = (j >> 8) % 9;
  int r = j / 2304;            // s*64+o
  out[i] = (__bf16)in[(r*256 + c)*9 + k];
}

// ---------- center-tap compact: wST [s*64+o][256][9] f32 -> [s][o][256] bf16 (tap 4)
__global__ void wcvtc_k(const float* __restrict__ w1, const float* __restrict__ w2,
                        __bf16* __restrict__ o1, __bf16* __restrict__ o2){
  int i = blockIdx.x*256 + threadIdx.x;
  if (i >= 49152) return;
  o1[i] = (__bf16)w1[i*9 + 4];
  o2[i] = (__bf16)w2[i*9 + 4];
}

// ---------- wa+wb -> bf16 (contiguous out)
__global__ void wcvtab_k(const float* __restrict__ wa, const float* __restrict__ wb,
                         __bf16* __restrict__ out){
  int i = blockIdx.x*256 + threadIdx.x;
  if (i >= 2*49152) return;
  out[i] = (__bf16)((i < 49152) ? wa[i] : wb[i - 49152]);
}

__global__ void wcvt_k(const float* __restrict__ in, __bf16* __restrict__ out, int total){
  int i = blockIdx.x*256 + threadIdx.x;
  if (i < total) out[i] = (__bf16)in[i];
}

// ---------- static graph transform: A_all[s] = ch3 + softmax_col(ch4) + PA
__global__ void a_all_k(const float* __restrict__ A, const float* __restrict__ PA,
                        float* __restrict__ Aall){
  int t = threadIdx.x;
  if (t >= 75) return;
  int s = t / 25, w = t % 25;
  float a[25], m[25];
  float mx = -3.4e38f;
  for (int v = 0; v < 25; ++v){
    float av = A[(s*25 + v)*25 + w];
    a[v] = av;
    float d = (v == w) ? 1.f : 0.f;
    float mm = (8.f*av*av*av*av - 4.f*av*av - 4.f*av + d) * 0.04f;
    m[v] = mm;
    mx = fmaxf(mx, mm);
  }
  float sum = 0.f;
  for (int v = 0; v < 25; ++v){ float e = __expf(m[v]-mx); m[v] = e; sum += e; }
  float inv = 1.f/sum;
  for (int v = 0; v < 25; ++v){
    float av = a[v];
    float d = (v == w) ? 1.f : 0.f;
    Aall[(s*25+v)*25 + w] = m[v]*inv + 4.f*av*av - av - 2.f*d + PA[(s*25+v)*25+w];
  }
}

// ---------- MFMA conv v3: wave = 64o x 128p (2 oq x 4 pq), depth-2 A prefetch
// grid (7 ptile256, 16 n, NP pairs), block 256 (4 waves = 2 which x 2 p-half)
template<int NTAPS, int CW, int WSTRIDE>
__global__ __launch_bounds__(256, 2) void conv3_k(const __bf16* __restrict__ xt,
    ConvPairs cp, __bf16* __restrict__ fbuf){
  extern __shared__ __bf16 sm[];
  constexpr int HALO  = (NTAPS==9) ? 100 : 0;
  constexpr int NROWS = 256 + 2*HALO;
  constexpr int GPR   = CW/8;            // 16B groups per LDS row
  constexpr int NCH   = 256/CW;
  constexpr int KS    = CW/16;
  constexpr int NSTEP = NTAPS*KS;
  int p0 = blockIdx.x*256;
  int n  = blockIdx.y;
  int pr = blockIdx.z;
  int tid = threadIdx.x;
  int lane = tid & 63;
  int wave = tid >> 6;
  int which = wave >> 1, ph = wave & 1;
  int h = lane >> 5, l31 = lane & 31;
  const __bf16* wgt = which ? cp.wB[pr] : cp.wA[pr];
  const float* bias = which ? cp.bB[pr] : cp.bA[pr];
  const __bf16* xtn = xt + (size_t)n*CTV;
  // lane-fixed weight base (o-quad 0 row = l31); o-quad 1 adds 32*WSTRIDE
  const __bf16* wl = wgt + (size_t)l31*WSTRIDE + h*8;

  f32x16 acc[2][4];   // [oq][pq]
  #pragma unroll
  for (int a=0;a<2;++a)
    #pragma unroll
    for (int b=0;b<4;++b)
      #pragma unroll
      for (int r=0;r<16;++r) acc[a][b][r] = 0.f;

  int rowbase = ph*128 + l31;

  for (int ch=0; ch<NCH; ++ch){
    // stage slab chunk: NROWS x CW bf16, group-swizzled
    for (int s2 = tid; s2 < NROWS*GPR; s2 += 256){
      int row = s2 / GPR, g = s2 % GPR;
      int pg = p0 - HALO + row;
      uint4 val = make_uint4(0u,0u,0u,0u);
      if ((unsigned)pg < 1600u)
        val = *(const uint4*)(xtn + (size_t)pg*256 + ch*CW + g*8);
      int gs = (g + row) & (GPR-1);
      *(uint4*)(sm + row*CW + gs*8) = val;
    }
    __syncthreads();
    const __bf16* wc = wl + ch*CW;
    auto ldA = [&](int s, v8bf& A0, v8bf& A1){
      int tap = s / KS, ks = s % KS;
      const __bf16* p = wc + (size_t)tap*256 + ks*16;
      A0 = *(const v8bf*)(p);
      A1 = *(const v8bf*)(p + (size_t)32*WSTRIDE);
    };
    v8bf a0[2], a1[2];
    ldA(0, a0[0], a1[0]);
    if (NSTEP > 1) ldA(1, a0[1], a1[1]);
    #pragma unroll
    for (int s=0; s<NSTEP; ++s){
      int tap = s / KS, ks = s % KS;
      int rowb = (NTAPS==9 ? tap*25 : 0) + rowbase;
      v8bf b[4];
      #pragma unroll
      for (int pq=0; pq<4; ++pq){
        int row = rowb + pq*32;
        int gs = ((ks*2 + h) + row) & (GPR-1);
        b[pq] = *(const v8bf*)(sm + row*CW + gs*8);
      }
      int cur = s & 1;
      v8bf A0 = a0[cur], A1 = a1[cur];
      if (s+2 < NSTEP) ldA(s+2, a0[cur], a1[cur]);
      #pragma unroll
      for (int pq=0; pq<4; ++pq){
        acc[0][pq] = __builtin_amdgcn_mfma_f32_32x32x16_bf16(A0, b[pq], acc[0][pq], 0,0,0);
        acc[1][pq] = __builtin_amdgcn_mfma_f32_32x32x16_bf16(A1, b[pq], acc[1][pq], 0,0,0);
      }
    }
    __syncthreads();
  }

  // epilogue: D col = l31 -> p, row = (r&3)+8*(r>>2)+4*h -> o
  __bf16* outb = fbuf + (size_t)(pr*2 + which)*NICTV + (size_t)n*ICTV;
  #pragma unroll
  for (int pq=0; pq<4; ++pq){
    int p = p0 + ph*128 + pq*32 + l31;
    if (p >= 1600) continue;
    #pragma unroll
    for (int oq=0; oq<2; ++oq){
      #pragma unroll
      for (int r=0; r<16; ++r){
        int og = oq*32 + (r&3) + 8*(r>>2) + 4*h;
        outb[(size_t)og*TV + p] = (__bf16)(acc[oq][pq][r] + bias[og]);
      }
    }
  }
}

// ---------- u GEMM v2: ubuf[br][n][p][o] = sum_c wd[br][o][c]*xt[n][p][c]
// grid (13 ptile128, 16 n, 3 br), block 256 (4 waves = o-slices of 64)
__global__ __launch_bounds__(256, 2) void ugemm2_k(const __bf16* __restrict__ xt,
    const __bf16* __restrict__ wdb, __bf16* __restrict__ ubuf){
  extern __shared__ __bf16 sm[];
  int p0 = blockIdx.x*128;
  int n  = blockIdx.y;
  int br = blockIdx.z;
  int tid = threadIdx.x;
  int lane = tid & 63;
  int os = tid >> 6;          // wave = o-slice (64 o)
  int h = lane >> 5, l31 = lane & 31;
  const __bf16* xtn = xt + (size_t)n*CTV;

  f32x16 acc[2][4];
  #pragma unroll
  for (int a=0;a<2;++a)
    #pragma unroll
    for (int b=0;b<4;++b)
      #pragma unroll
      for (int r=0;r<16;++r) acc[a][b][r] = 0.f;

  // stage 128 x 256 slab (64 KB), group-swizzled
  for (int s2 = tid; s2 < 128*32; s2 += 256){
    int row = s2 >> 5, g = s2 & 31;
    int pg = p0 + row;
    uint4 val = make_uint4(0u,0u,0u,0u);
    if (pg < 1600)
      val = *(const uint4*)(xtn + (size_t)pg*256 + g*8);
    int gs = (g + row) & 31;
    *(uint4*)(sm + row*256 + gs*8) = val;
  }
  __syncthreads();

  const __bf16* wl = wdb + ((size_t)br*256 + os*64 + l31)*256 + h*8;
  auto ldA = [&](int ks, v8bf& A0, v8bf& A1){
    A0 = *(const v8bf*)(wl + ks*16);
    A1 = *(const v8bf*)(wl + (size_t)32*256 + ks*16);
  };
  v8bf a0[2], a1[2];
  ldA(0, a0[0], a1[0]);
  ldA(1, a0[1], a1[1]);
  #pragma unroll
  for (int ks=0; ks<16; ++ks){
    v8bf b[4];
    #pragma unroll
    for (int pq=0; pq<4; ++pq){
      int row = pq*32 + l31;
      int gs = ((ks*2 + h) + row) & 31;
      b[pq] = *(const v8bf*)(sm + row*256 + gs*8);
    }
    int cur = ks & 1;
    v8bf A0 = a0[cur], A1 = a1[cur];
    if (ks+2 < 16) ldA(ks+2, a0[cur], a1[cur]);
    #pragma unroll
    for (int pq=0; pq<4; ++pq){
      acc[0][pq] = __builtin_amdgcn_mfma_f32_32x32x16_bf16(A0, b[pq], acc[0][pq], 0,0,0);
      acc[1][pq] = __builtin_amdgcn_mfma_f32_32x32x16_bf16(A1, b[pq], acc[1][pq], 0,0,0);
    }
  }

  // store o-contiguous, 4-wide packs
  #pragma unroll
  for (int pq=0; pq<4; ++pq){
    int p = p0 + pq*32 + l31;
    if (p >= 1600) continue;
    __bf16* out = ubuf + ((size_t)(br*NN + n)*TV + p)*256;
    #pragma unroll
    for (int oq=0; oq<2; ++oq){
      #pragma unroll
      for (int g=0; g<4; ++g){
        int og = os*64 + oq*32 + 8*g + 4*h;
        v4bf pk;
        pk[0] = (__bf16)acc[oq][pq][4*g+0];
        pk[1] = (__bf16)acc[oq][pq][4*g+1];
        pk[2] = (__bf16)acc[oq][pq][4*g+2];
        pk[3] = (__bf16)acc[oq][pq][4*g+3];
        *(v4bf*)(out + og) = pk;
      }
    }
  }
}

// ---------- scores mega: grid (16 chunk, 16 n, P pairs)
__global__ __launch_bounds__(640) void scores2_k(const __bf16* __restrict__ fbuf,
                                                 float* __restrict__ part, int pairbase){
  __shared__ float s1[64*26];
  __shared__ float s2[64*26];
  int chunk = blockIdx.x, n = blockIdx.y, pr = blockIdx.z;
  int tid = threadIdx.x;
  const __bf16* f1 = fbuf + (size_t)(pr*2)*NICTV   + (size_t)n*ICTV;
  const __bf16* f2 = fbuf + (size_t)(pr*2+1)*NICTV + (size_t)n*ICTV;
  int v = tid/25, w = tid%25;
  float acc = 0.f;
  for (int sub=0; sub<4; ++sub){
    int q0 = chunk*256 + sub*64;
    for (int l=tid; l<1600; l+=640){
      int qq = l/25, vv = l%25;
      s1[qq*26+vv] = (float)f1[(q0+qq)*25+vv];
      s2[qq*26+vv] = (float)f2[(q0+qq)*25+vv];
    }
    __syncthreads();
    if (tid < 625){
      #pragma unroll 8
      for (int q=0;q<64;++q) acc = fmaf(s1[q*26+v], s2[q*26+w], acc);
    }
    __syncthreads();
  }
  if (tid < 625) part[(((size_t)(pairbase+pr)*NN + n)*16 + chunk)*625 + tid] = acc;
}

// ---------- reduce all 9 pairs: softmax each, sum into branches, Ai3 = Aall + sums
__global__ __launch_bounds__(64) void reduce_all_k(const float* __restrict__ part,
    const float* __restrict__ Aall, float* __restrict__ Ai3){
  const int pairbr[9] = {0,1,2,0,2, 0,1,2,1};
  int n = blockIdx.x, w = blockIdx.y;
  int lane = threadIdx.x;
  float accbr[3] = {0.f, 0.f, 0.f};
  for (int pr=0; pr<9; ++pr){
    float s = 0.f;
    if (lane < 25){
      const float* pp = part + (((size_t)pr*NN + n)*16)*625 + lane*25 + w;
      #pragma unroll
      for (int ch=0; ch<16; ++ch) s += pp[ch*625];
    }
    s *= (1.f/4096.f);
    float mval = (lane<25) ? s : -3.4e38f;
    #pragma unroll
    for (int d=32; d>0; d>>=1) mval = fmaxf(mval, __shfl_xor(mval, d));
    float e = (lane<25) ? __expf(s - mval) : 0.f;
    float sum = e;
    #pragma unroll
    for (int d=32; d>0; d>>=1) sum += __shfl_xor(sum, d);
    accbr[pairbr[pr]] += e / sum;
  }
  if (lane < 25){
    #pragma unroll
    for (int br=0; br<3; ++br)
      Ai3[((size_t)br*NN + n)*625 + lane*25 + w] =
        Aall[br*625 + lane*25 + w] + accbr[br];
  }
}

// ---------- epilogue: y + BN + residual + relu
__global__ __launch_bounds__(256) void yep_k(const float* __restrict__ x,
    const float* __restrict__ Ai3, const __bf16* __restrict__ ubuf,
    const float* __restrict__ bd, const float* __restrict__ gamma,
    const float* __restrict__ beta, const float* __restrict__ bnm,
    const float* __restrict__ bnv, float* __restrict__ out){
  __shared__ float ais[3][25*28];
  int t = blockIdx.x, n = blockIdx.y, o = threadIdx.x;
  for (int l=o; l<1875; l+=256){
    int br = l/625, r = l%625;
    ais[br][(r/25)*28 + (r%25)] = Ai3[((size_t)br*NN + n)*625 + r];
  }
  __syncthreads();
  float y[25];
  #pragma unroll
  for (int w=0;w<25;++w) y[w]=0.f;
  for (int br=0; br<3; ++br){
    const __bf16* up = ubuf + ((size_t)(br*NN + n)*TV + t*25)*256 + o;
    float uv[25];
    #pragma unroll
    for (int v=0;v<25;++v) uv[v] = (float)up[(size_t)v*256];
    float bb = bd[br*256 + o];
    const float* ab = ais[br];
    for (int w=0; w<25; ++w){
      float a = bb;
      #pragma unroll
      for (int v=0;v<25;++v) a = fmaf(uv[v], ab[v*28+w], a);
      y[w] += a;
    }
  }
  float sc = gamma[o] * rsqrtf(bnv[o] + 1e-5f);
  float m  = bnm[o], be = beta[o];
  const float* xr = x + (size_t)n*CTV + (size_t)o*TV + t*25;
  float* orow = out + (size_t)n*CTV + (size_t)o*TV + t*25;
  #pragma unroll
  for (int w=0; w<25; ++w)
    orow[w] = fmaxf((y[w] - m)*sc + be + xr[w], 0.f);
}

extern "C" void kernel_launch(void* const* d_in, const int* in_sizes, int n_in,
                              void* d_out, int out_size, void* d_ws, size_t ws_size,
                              hipStream_t stream) {
  const float* x     = (const float*)d_in[0];
  const float* A     = (const float*)d_in[1];
  const float* PA    = (const float*)d_in[2];
  const float* wa    = (const float*)d_in[3];
  const float* ba    = (const float*)d_in[4];
  const float* wb    = (const float*)d_in[5];
  const float* bb    = (const float*)d_in[6];
  const float* wT1   = (const float*)d_in[7];
  const float* bT1   = (const float*)d_in[8];
  const float* wT2   = (const float*)d_in[9];
  const float* bT2   = (const float*)d_in[10];
  const float* wST11 = (const float*)d_in[11];
  const float* bST11 = (const float*)d_in[12];
  const float* wST12 = (const float*)d_in[13];
  const float* bST12 = (const float*)d_in[14];
  const float* wd    = (const float*)d_in[15];
  const float* bd    = (const float*)d_in[16];
  const float* gamma = (const float*)d_in[17];
  const float* beta  = (const float*)d_in[18];
  const float* bnm   = (const float*)d_in[19];
  const float* bnv   = (const float*)d_in[20];

  char* W = (char*)d_ws;
  float*  Aall = (float*)W;  W += 8192;
  float*  Ai3  = (float*)W;  W += 122880;    // 3*16*625 f32 (padded)
  __bf16* wab  = (__bf16*)W; W += 98304;     // 3*64*256 bf16
  __bf16* wbb  = (__bf16*)W; W += 98304;
  __bf16* wT1b = (__bf16*)W; W += 884736;    // 3*64*9*256 bf16 x4 contiguous
  __bf16* wT2b = (__bf16*)W; W += 884736;
  __bf16* wS1b = (__bf16*)W; W += 884736;
  __bf16* wS2b = (__bf16*)W; W += 884736;
  __bf16* wS1c = (__bf16*)W; W += 98304;     // center-tap compact [3][64][256]
  __bf16* wS2c = (__bf16*)W; W += 98304;
  __bf16* wdb  = (__bf16*)W; W += 393216;    // 3*256*256 bf16
  __bf16* xt   = (__bf16*)W; W += 13107200;  // 16*1600*256 bf16
  char* R = W;               W += 39321600;  // fbuf (10 slices, 32.8MB) / ubuf (39.3MB)
  float*  part = (float*)W;  W += 23040000;  // 9*16*16*625 f32
  __bf16* fbuf = (__bf16*)R;
  __bf16* ubuf = (__bf16*)R;
  // total ws ~62.9 MB

  // prep
  xt_k<<<dim3(25,4,16), 256, 0, stream>>>(x, xt);
  wcvt9m_k<<<(4*442368+255)/256, 256, 0, stream>>>(wT1, wT2, wST11, wST12, wT1b);
  wcvtc_k<<<192, 256, 0, stream>>>(wST11, wST12, wS1c, wS2c);
  wcvtab_k<<<(2*49152+255)/256, 256, 0, stream>>>(wa, wb, wab);
  wcvt_k<<<768, 256, 0, stream>>>(wd, wdb, 196608);
  a_all_k<<<1, 128, 0, stream>>>(A, PA, Aall);

  // phase 1: all "1x1" pairs (A x3, ST-even x2 via compact center-tap) -> pairs 0..4
  {
    ConvPairs cp;
    for (int i=0;i<3;++i){
      cp.wA[i] = wab + i*16384;  cp.wB[i] = wbb + i*16384;
      cp.bA[i] = ba + i*64;      cp.bB[i] = bb + i*64;
    }
    int evens[2] = {0, 2};
    for (int j=0;j<2;++j){
      int i = evens[j];
      cp.wA[3+j] = wS1c + i*16384;  cp.wB[3+j] = wS2c + i*16384;
      cp.bA[3+j] = bST11 + i*64;    cp.bB[3+j] = bST12 + i*64;
    }
    conv3_k<1,128,256><<<dim3(7,16,5), 256, 256*128*2, stream>>>(xt, cp, fbuf);
    scores2_k<<<dim3(16,16,5), 640, 0, stream>>>(fbuf, part, 0);
  }

  // phase 2: all 9-tap pairs (T x3, ST-odd x1) -> pairs 5..8
  {
    ConvPairs cp;
    for (int i=0;i<3;++i){
      cp.wA[i] = wT1b + i*147456;  cp.wB[i] = wT2b + i*147456;
      cp.bA[i] = bT1 + i*64;       cp.bB[i] = bT2 + i*64;
    }
    cp.wA[3] = wS1b + 1*147456;  cp.wB[3] = wS2b + 1*147456;
    cp.bA[3] = bST11 + 1*64;     cp.bB[3] = bST12 + 1*64;
    cp.wA[4] = cp.wA[3]; cp.wB[4] = cp.wB[3]; cp.bA[4] = cp.bA[3]; cp.bB[4] = cp.bB[3];
    conv3_k<9,64,2304><<<dim3(7,16,4), 256, 456*64*2, stream>>>(xt, cp, fbuf);
    scores2_k<<<dim3(16,16,4), 640, 0, stream>>>(fbuf, part, 5);
  }

  // u GEMM (overwrites fbuf region — fbuf dead after phase-2 scores)
  ugemm2_k<<<dim3(13,16,3), 256, 128*256*2, stream>>>(xt, wdb, ubuf);
  // all-pair softmax reduce -> Ai3
  reduce_all_k<<<dim3(16,25), 64, 0, stream>>>(part, Aall, Ai3);
  // epilogue
  yep_k<<<dim3(64,16), 256, 0, stream>>>(x, Ai3, ubuf, bd, gamma, beta, bnm, bnv,
                                         (float*)d_out);
}